// Round 8
// baseline (630.726 us; speedup 1.0000x reference)
//
#include <hip/hip_runtime.h>
#include <hip/hip_bf16.h>
#include <math.h>

// ---------------------------------------------------------------------------
// Shapes (fixed by the problem)
// ---------------------------------------------------------------------------
#define B_    4
#define S_    512
#define D_    1024
#define T_    2048          // B*S tokens
#define H_    16
#define HD_   64
#define E_    8
#define HID_  1792
#define D3_   3072
#define GU_   (2 * HID_)    // 3584 interleaved gate/up columns

typedef unsigned short ushort_t;
typedef __bf16 bf16x8 __attribute__((ext_vector_type(8)));
typedef float  floatx4 __attribute__((ext_vector_type(4)));

__device__ inline float bf2f(ushort_t u) {
    return __uint_as_float(((unsigned)u) << 16);
}
__device__ inline ushort_t f2bf(float f) {
    __hip_bfloat16 h = __float2bfloat16(f);
    return __builtin_bit_cast(ushort_t, h);
}

// two-word bf16 split: x ~= hi + lo with combined rel error ~2^-17.
// hi = truncated-bf16(x) (exact prefix), lo = rne-bf16(x - hi).
__device__ __forceinline__ void split2(float x, ushort_t& h, ushort_t& l) {
    const unsigned ub = __float_as_uint(x);
    h = (ushort_t)(ub >> 16);
    l = f2bf(x - __uint_as_float(ub & 0xFFFF0000u));
}

// async 16B/lane global->LDS; lds dest wave-uniform base (+lane*16 by HW)
__device__ __forceinline__ void gl2lds16(const ushort_t* g, ushort_t* l) {
    __builtin_amdgcn_global_load_lds(
        (const __attribute__((address_space(1))) void*)g,
        (__attribute__((address_space(3))) void*)l, 16, 0, 0);
}

// ---------------------------------------------------------------------------
// Transpose + fp32->bf16: in (z,R,C) f32 -> out[z*outEstride + (c*mul+add)*R + r]
// ---------------------------------------------------------------------------
__global__ __launch_bounds__(256) void transpose_bf16_kernel(
    const float* __restrict__ in, ushort_t* __restrict__ out,
    int R, int C, int mul, int add, long outEstride)
{
    __shared__ float tile[32][33];
    const int bx = blockIdx.x * 32;           // c
    const int by = blockIdx.y * 32;           // r
    const size_t iofs = (size_t)blockIdx.z * R * C;
    const size_t oofs = (size_t)blockIdx.z * outEstride;
    const int tx = threadIdx.x & 31;
    const int ty = threadIdx.x >> 5;          // 0..7
#pragma unroll
    for (int i = 0; i < 4; i++) {
        int r = by + ty + i * 8;
        tile[ty + i * 8][tx] = in[iofs + (size_t)r * C + bx + tx];
    }
    __syncthreads();
#pragma unroll
    for (int i = 0; i < 4; i++) {
        int c = bx + ty + i * 8;
        out[oofs + (size_t)(c * mul + add) * R + by + tx] = f2bf(tile[tx][ty + i * 8]);
    }
}

// ---------------------------------------------------------------------------
// Transpose + fp32 -> two-word bf16 planes: in (R,C) f32 -> outh/outl[c*R + r]
// ---------------------------------------------------------------------------
__global__ __launch_bounds__(256) void transpose_split_kernel(
    const float* __restrict__ in, ushort_t* __restrict__ outh,
    ushort_t* __restrict__ outl, int R, int C)
{
    __shared__ float tile[32][33];
    const int bx = blockIdx.x * 32;           // c
    const int by = blockIdx.y * 32;           // r
    const int tx = threadIdx.x & 31;
    const int ty = threadIdx.x >> 5;          // 0..7
#pragma unroll
    for (int i = 0; i < 4; i++) {
        int r = by + ty + i * 8;
        tile[ty + i * 8][tx] = in[(size_t)r * C + bx + tx];
    }
    __syncthreads();
#pragma unroll
    for (int i = 0; i < 4; i++) {
        const int c = bx + ty + i * 8;
        const float v = tile[tx][ty + i * 8];
        ushort_t hh, ll;
        split2(v, hh, ll);
        outh[(size_t)c * R + by + tx] = hh;
        outl[(size_t)c * R + by + tx] = ll;
    }
}

// ---------------------------------------------------------------------------
// LayerNorm: x (rows x 1024) f32 -> optional bf16 out and/or hi/lo bf16 planes
// ---------------------------------------------------------------------------
__global__ __launch_bounds__(256) void ln_kernel(
    const float* __restrict__ x, const float* __restrict__ g,
    const float* __restrict__ b, ushort_t* __restrict__ outb,
    ushort_t* __restrict__ outh, ushort_t* __restrict__ outl)
{
    const int t = blockIdx.x;
    const int tid = threadIdx.x;
    const int wave = tid >> 6, lane = tid & 63;
    const float4 v = ((const float4*)(x + (size_t)t * D_))[tid];

    float s = v.x + v.y + v.z + v.w;
#pragma unroll
    for (int off = 32; off; off >>= 1) s += __shfl_xor(s, off);
    __shared__ float red1[4];
    __shared__ float red2[4];
    if (lane == 0) red1[wave] = s;
    __syncthreads();
    const float mu = (red1[0] + red1[1] + red1[2] + red1[3]) * (1.0f / D_);

    const float dx = v.x - mu, dy = v.y - mu, dz = v.z - mu, dw = v.w - mu;
    float vs = dx * dx + dy * dy + dz * dz + dw * dw;
#pragma unroll
    for (int off = 32; off; off >>= 1) vs += __shfl_xor(vs, off);
    if (lane == 0) red2[wave] = vs;
    __syncthreads();
    const float var = (red2[0] + red2[1] + red2[2] + red2[3]) * (1.0f / D_);
    const float rs = 1.0f / sqrtf(var + 1e-5f);

    const float4 gg = ((const float4*)g)[tid];
    const float4 bb = ((const float4*)b)[tid];
    float4 o;
    o.x = dx * rs * gg.x + bb.x;
    o.y = dy * rs * gg.y + bb.y;
    o.z = dz * rs * gg.z + bb.z;
    o.w = dw * rs * gg.w + bb.w;
    if (outb) {
        ushort4 ob;
        ob.x = f2bf(o.x); ob.y = f2bf(o.y); ob.z = f2bf(o.z); ob.w = f2bf(o.w);
        ((ushort4*)(outb + (size_t)t * D_))[tid] = ob;
    }
    if (outh) {
        ushort4 oh, ol;
        split2(o.x, oh.x, ol.x); split2(o.y, oh.y, ol.y);
        split2(o.z, oh.z, ol.z); split2(o.w, oh.w, ol.w);
        ((ushort4*)(outh + (size_t)t * D_))[tid] = oh;
        ((ushort4*)(outl + (size_t)t * D_))[tid] = ol;
    }
}

// ---------------------------------------------------------------------------
// Two-word bf16 MFMA GEMM: C[M x ncols] = (Ah+Al)[M x 1024] · (Bh+Bl)[N x 1024]^T
// (+ optional f32 residual, optional second output). 128x128 tile, BK=32,
// 4 waves, 4x4 16x16x32 MFMAs per wave, 3 per product (hh + lh + hl).
// ---------------------------------------------------------------------------
__global__ __launch_bounds__(256) void gemm2w_kernel(
    const ushort_t* __restrict__ Ah, const ushort_t* __restrict__ Al,
    const ushort_t* __restrict__ Bh, const ushort_t* __restrict__ Bl,
    const float* __restrict__ res, float* __restrict__ C,
    float* __restrict__ C2, int ncols)
{
    const int row0 = blockIdx.y * 128, col0 = blockIdx.x * 128;

    __shared__ __align__(16) ushort_t Ash[128 * 32], Asl[128 * 32];
    __shared__ __align__(16) ushort_t Bsh[128 * 32], Bsl[128 * 32];
    const int tid = threadIdx.x, w = tid >> 6, lane = tid & 63;
    const int lr = lane >> 2, lc = (lane & 3) * 8;
    const int wm = (w >> 1) * 64, wn = (w & 1) * 64;
    const int lm = lane & 15, lq = lane >> 4;

    floatx4 acc[4][4] = {};

    const ushort_t* Aph = Ah + (size_t)(row0 + w * 16 + lr) * D_ + lc;
    const ushort_t* Apl = Al + (size_t)(row0 + w * 16 + lr) * D_ + lc;
    const ushort_t* Bph = Bh + (size_t)(col0 + w * 16 + lr) * D_ + lc;
    const ushort_t* Bpl = Bl + (size_t)(col0 + w * 16 + lr) * D_ + lc;
    ushort_t* lAh = Ash + w * 512;
    ushort_t* lAl = Asl + w * 512;
    ushort_t* lBh = Bsh + w * 512;
    ushort_t* lBl = Bsl + w * 512;

    for (int k0 = 0; k0 < D_; k0 += 32) {
        __syncthreads();
        gl2lds16(Aph + k0, lAh);
        gl2lds16(Aph + k0 + (size_t)64 * D_, lAh + 2048);
        gl2lds16(Apl + k0, lAl);
        gl2lds16(Apl + k0 + (size_t)64 * D_, lAl + 2048);
        gl2lds16(Bph + k0, lBh);
        gl2lds16(Bph + k0 + (size_t)64 * D_, lBh + 2048);
        gl2lds16(Bpl + k0, lBl);
        gl2lds16(Bpl + k0 + (size_t)64 * D_, lBl + 2048);
        __syncthreads();
        bf16x8 ah[4], al[4], bh16[4], bl16[4];
#pragma unroll
        for (int i = 0; i < 4; i++) {
            ah[i] = *(const bf16x8*)(Ash + (wm + i * 16 + lm) * 32 + lq * 8);
            al[i] = *(const bf16x8*)(Asl + (wm + i * 16 + lm) * 32 + lq * 8);
        }
#pragma unroll
        for (int j = 0; j < 4; j++) {
            bh16[j] = *(const bf16x8*)(Bsh + (wn + j * 16 + lm) * 32 + lq * 8);
            bl16[j] = *(const bf16x8*)(Bsl + (wn + j * 16 + lm) * 32 + lq * 8);
        }
#pragma unroll
        for (int i = 0; i < 4; i++)
#pragma unroll
            for (int j = 0; j < 4; j++) {
                acc[i][j] = __builtin_amdgcn_mfma_f32_16x16x32_bf16(ah[i], bh16[j], acc[i][j], 0, 0, 0);
                acc[i][j] = __builtin_amdgcn_mfma_f32_16x16x32_bf16(al[i], bh16[j], acc[i][j], 0, 0, 0);
                acc[i][j] = __builtin_amdgcn_mfma_f32_16x16x32_bf16(ah[i], bl16[j], acc[i][j], 0, 0, 0);
            }
    }

#pragma unroll
    for (int i = 0; i < 4; i++)
#pragma unroll
        for (int r = 0; r < 4; r++) {
            const int row = row0 + wm + i * 16 + lq * 4 + r;
#pragma unroll
            for (int j = 0; j < 4; j++) {
                const int col = col0 + wn + j * 16 + lm;
                const size_t idx = (size_t)row * ncols + col;
                float o = acc[i][j][r];
                if (res) o += res[idx];
                C[idx] = o;
                if (C2) C2[idx] = o;
            }
        }
}

// ---------------------------------------------------------------------------
// QKV GEMM with fused RoPE + two-word split + V-transpose epilogue.
// C = (xnh+xnl)[2048 x 1024] · (wqkvTh+wqkvTl)[3072 x 1024]^T.
// col < 2048 (q,k): rotation pairs are ADJACENT cols = adjacent lanes
// (partner via __shfl_xor(v,1)); rotated value -> split2 -> qkh/qkl[t][col].
// col >= 2048 (V): split2 -> vT[bh][d][s] planes (4 consecutive s per lane).
// Same f32 values as the old qkvP0 + rope_split + vt_split path ->
// bit-identical outputs, minus 25MB write + 33MB read + 2 launches.
// ---------------------------------------------------------------------------
__global__ __launch_bounds__(256) void qkv_rope_gemm_kernel(
    const ushort_t* __restrict__ Ah, const ushort_t* __restrict__ Al,
    const ushort_t* __restrict__ Bh, const ushort_t* __restrict__ Bl,
    const float* __restrict__ ctab, const float* __restrict__ stab,
    ushort_t* __restrict__ qkh, ushort_t* __restrict__ qkl,
    ushort_t* __restrict__ vTh, ushort_t* __restrict__ vTl)
{
    const int row0 = blockIdx.y * 128, col0 = blockIdx.x * 128;

    __shared__ __align__(16) ushort_t Ash[128 * 32], Asl[128 * 32];
    __shared__ __align__(16) ushort_t Bsh[128 * 32], Bsl[128 * 32];
    const int tid = threadIdx.x, w = tid >> 6, lane = tid & 63;
    const int lr = lane >> 2, lc = (lane & 3) * 8;
    const int wm = (w >> 1) * 64, wn = (w & 1) * 64;
    const int lm = lane & 15, lq = lane >> 4;

    floatx4 acc[4][4] = {};

    const ushort_t* Aph = Ah + (size_t)(row0 + w * 16 + lr) * D_ + lc;
    const ushort_t* Apl = Al + (size_t)(row0 + w * 16 + lr) * D_ + lc;
    const ushort_t* Bph = Bh + (size_t)(col0 + w * 16 + lr) * D_ + lc;
    const ushort_t* Bpl = Bl + (size_t)(col0 + w * 16 + lr) * D_ + lc;
    ushort_t* lAh = Ash + w * 512;
    ushort_t* lAl = Asl + w * 512;
    ushort_t* lBh = Bsh + w * 512;
    ushort_t* lBl = Bsl + w * 512;

    for (int k0 = 0; k0 < D_; k0 += 32) {
        __syncthreads();
        gl2lds16(Aph + k0, lAh);
        gl2lds16(Aph + k0 + (size_t)64 * D_, lAh + 2048);
        gl2lds16(Apl + k0, lAl);
        gl2lds16(Apl + k0 + (size_t)64 * D_, lAl + 2048);
        gl2lds16(Bph + k0, lBh);
        gl2lds16(Bph + k0 + (size_t)64 * D_, lBh + 2048);
        gl2lds16(Bpl + k0, lBl);
        gl2lds16(Bpl + k0 + (size_t)64 * D_, lBl + 2048);
        __syncthreads();
        bf16x8 ah[4], al[4], bh16[4], bl16[4];
#pragma unroll
        for (int i = 0; i < 4; i++) {
            ah[i] = *(const bf16x8*)(Ash + (wm + i * 16 + lm) * 32 + lq * 8);
            al[i] = *(const bf16x8*)(Asl + (wm + i * 16 + lm) * 32 + lq * 8);
        }
#pragma unroll
        for (int j = 0; j < 4; j++) {
            bh16[j] = *(const bf16x8*)(Bsh + (wn + j * 16 + lm) * 32 + lq * 8);
            bl16[j] = *(const bf16x8*)(Bsl + (wn + j * 16 + lm) * 32 + lq * 8);
        }
#pragma unroll
        for (int i = 0; i < 4; i++)
#pragma unroll
            for (int j = 0; j < 4; j++) {
                acc[i][j] = __builtin_amdgcn_mfma_f32_16x16x32_bf16(ah[i], bh16[j], acc[i][j], 0, 0, 0);
                acc[i][j] = __builtin_amdgcn_mfma_f32_16x16x32_bf16(al[i], bh16[j], acc[i][j], 0, 0, 0);
                acc[i][j] = __builtin_amdgcn_mfma_f32_16x16x32_bf16(ah[i], bl16[j], acc[i][j], 0, 0, 0);
            }
    }

    const bool isV = (col0 >= 2 * D_);   // block-uniform (D3 tiles split at 2048)
#pragma unroll
    for (int i = 0; i < 4; i++)
#pragma unroll
        for (int j = 0; j < 4; j++) {
            const int col = col0 + wn + j * 16 + lm;
#pragma unroll
            for (int r = 0; r < 4; r++) {
                const int row = row0 + wm + i * 16 + lq * 4 + r;   // token t
                float v = acc[i][j][r];
                if (!isV) {
                    // RoPE: partner col = col^1 lives in lane^1 (same i,j,r)
                    const float vp = __shfl_xor(v, 1);
                    const int pair = (col & 63) >> 1;
                    const int s = row & (S_ - 1);
                    const float cc = ctab[s * 32 + pair];
                    const float sn = stab[s * 32 + pair];
                    v = (lm & 1) ? fmaf(vp, sn, v * cc)
                                 : fmaf(-vp, sn, v * cc);
                    ushort_t hh, ll;
                    split2(v, hh, ll);
                    qkh[(size_t)row * 2048 + col] = hh;
                    qkl[(size_t)row * 2048 + col] = ll;
                } else {
                    ushort_t hh, ll;
                    split2(v, hh, ll);
                    const int dg = col - 2 * D_;           // 0..1023
                    const int bh = (row >> 9) * 16 + (dg >> 6);
                    const int d  = dg & 63;
                    const int s  = row & (S_ - 1);
                    vTh[((size_t)bh * 64 + d) * 512 + s] = hh;
                    vTl[((size_t)bh * 64 + d) * 512 + s] = ll;
                }
            }
        }
}

// ---------------------------------------------------------------------------
// Routed fused gate+up MoE GEMM: rows gathered from per-expert token lists.
// Single-buffer 2-barrier staging (proven structure).
// ---------------------------------------------------------------------------
__global__ __launch_bounds__(256) void gateup_idx_kernel(
    const ushort_t* __restrict__ A, const ushort_t* __restrict__ Bgu,
    const int* __restrict__ cnt, const int* __restrict__ tok,
    ushort_t* __restrict__ Hc)
{
    const int e = blockIdx.z;
    const int cntE = cnt[e];
    const int row0 = blockIdx.y * 128;
    if (row0 >= cntE) return;
    const int col0 = blockIdx.x * 128;
    const ushort_t* Bt = Bgu + (size_t)e * GU_ * D_;
    ushort_t* Hp = Hc + (size_t)e * T_ * HID_;

    __shared__ __align__(16) ushort_t As[128 * 32];
    __shared__ __align__(16) ushort_t Bs[128 * 32];
    const int tid = threadIdx.x, w = tid >> 6, lane = tid & 63;
    const int lr = lane >> 2, lc = (lane & 3) * 8;
    const int wm = (w >> 1) * 64, wn = (w & 1) * 64;
    const int lm = lane & 15, lq = lane >> 4;

    floatx4 acc[4][4] = {};

    int r0c = row0 + w * 16 + lr;  if (r0c > cntE - 1) r0c = cntE - 1;
    int r1c = row0 + 64 + w * 16 + lr; if (r1c > cntE - 1) r1c = cntE - 1;
    const ushort_t* Ap0 = A + (size_t)tok[e * T_ + r0c] * D_ + lc;
    const ushort_t* Ap1 = A + (size_t)tok[e * T_ + r1c] * D_ + lc;
    const ushort_t* Bp = Bt + (size_t)(col0 + w * 16 + lr) * D_ + lc;
    ushort_t* lA = As + w * 512;
    ushort_t* lB = Bs + w * 512;

    for (int k0 = 0; k0 < D_; k0 += 32) {
        __syncthreads();
        gl2lds16(Ap0 + k0, lA);
        gl2lds16(Ap1 + k0, lA + 2048);
        gl2lds16(Bp + k0, lB);
        gl2lds16(Bp + k0 + (size_t)64 * D_, lB + 2048);
        __syncthreads();
        bf16x8 a[4], b[4];
#pragma unroll
        for (int i = 0; i < 4; i++)
            a[i] = *(const bf16x8*)(As + (wm + i * 16 + lm) * 32 + lq * 8);
#pragma unroll
        for (int j = 0; j < 4; j++)
            b[j] = *(const bf16x8*)(Bs + (wn + j * 16 + lm) * 32 + lq * 8);
#pragma unroll
        for (int i = 0; i < 4; i++)
#pragma unroll
            for (int j = 0; j < 4; j++)
                acc[i][j] = __builtin_amdgcn_mfma_f32_16x16x32_bf16(a[i], b[j], acc[i][j], 0, 0, 0);
    }

    // epilogue: adjacent lanes hold (gate, up) for the same hidden unit
#pragma unroll
    for (int i = 0; i < 4; i++)
#pragma unroll
        for (int j = 0; j < 4; j++)
#pragma unroll
            for (int r = 0; r < 4; r++) {
                const float v = acc[i][j][r];
                const float vp = __shfl_xor(v, 1);
                const float g = (lm & 1) ? vp : v;
                const float u = (lm & 1) ? v : vp;
                const float h = g / (1.f + __expf(-g)) * u;
                if (!(lm & 1)) {
                    const int row = row0 + wm + i * 16 + lq * 4 + r;
                    const int col = col0 + wn + j * 16 + lm;    // even
                    Hp[(size_t)row * HID_ + (col >> 1)] = f2bf(h);
                }
            }
}

// ---------------------------------------------------------------------------
// Routed MoE down GEMM, split-K: out[tok[r]] += wt[r] * (Hc[e] @ wd[e]^T).
// grid (8, 16, E*2): z -> (expert, k-slice of HID/2). Single-buffer staging.
// ---------------------------------------------------------------------------
__global__ __launch_bounds__(256) void down_idx_kernel(
    const ushort_t* __restrict__ Hc, const ushort_t* __restrict__ Wd,
    const int* __restrict__ cnt, const int* __restrict__ tok,
    const float* __restrict__ wt, float* __restrict__ out)
{
    const int e = blockIdx.z >> 1;
    const int ks = blockIdx.z & 1;
    const int cntE = cnt[e];
    const int row0 = blockIdx.y * 128;
    if (row0 >= cntE) return;
    const int col0 = blockIdx.x * 128;
    const int kBegin = ks * (HID_ / 2);
    const ushort_t* A = Hc + (size_t)e * T_ * HID_;
    const ushort_t* Bt = Wd + (size_t)e * D_ * HID_;

    __shared__ __align__(16) ushort_t As[128 * 32];
    __shared__ __align__(16) ushort_t Bs[128 * 32];
    const int tid = threadIdx.x, w = tid >> 6, lane = tid & 63;
    const int lr = lane >> 2, lc = (lane & 3) * 8;
    const int wm = (w >> 1) * 64, wn = (w & 1) * 64;
    const int lm = lane & 15, lq = lane >> 4;

    floatx4 acc[4][4] = {};

    const ushort_t* Ap = A + (size_t)(row0 + w * 16 + lr) * HID_ + kBegin + lc;
    const ushort_t* Bp = Bt + (size_t)(col0 + w * 16 + lr) * HID_ + kBegin + lc;
    ushort_t* lA = As + w * 512;
    ushort_t* lB = Bs + w * 512;

    for (int k0 = 0; k0 < HID_ / 2; k0 += 32) {
        __syncthreads();
        gl2lds16(Ap + k0, lA);
        gl2lds16(Ap + k0 + (size_t)64 * HID_, lA + 2048);
        gl2lds16(Bp + k0, lB);
        gl2lds16(Bp + k0 + (size_t)64 * HID_, lB + 2048);
        __syncthreads();
        bf16x8 a[4], b[4];
#pragma unroll
        for (int i = 0; i < 4; i++)
            a[i] = *(const bf16x8*)(As + (wm + i * 16 + lm) * 32 + lq * 8);
#pragma unroll
        for (int j = 0; j < 4; j++)
            b[j] = *(const bf16x8*)(Bs + (wn + j * 16 + lm) * 32 + lq * 8);
#pragma unroll
        for (int i = 0; i < 4; i++)
#pragma unroll
            for (int j = 0; j < 4; j++)
                acc[i][j] = __builtin_amdgcn_mfma_f32_16x16x32_bf16(a[i], b[j], acc[i][j], 0, 0, 0);
    }

#pragma unroll
    for (int i = 0; i < 4; i++)
#pragma unroll
        for (int r = 0; r < 4; r++) {
            const int row = row0 + wm + i * 16 + lq * 4 + r;
            if (row < cntE) {
                const int t = tok[e * T_ + row];
                const float scale = wt[e * T_ + row];
#pragma unroll
                for (int j = 0; j < 4; j++) {
                    const int col = col0 + wn + j * 16 + lm;
                    atomicAdd(&out[(size_t)t * D_ + col], scale * acc[i][j][r]);
                }
            }
        }
}

// ---------------------------------------------------------------------------
// RoPE cos/sin tables (np f32 semantics via f64 pow/cos/sin)
// ---------------------------------------------------------------------------
__global__ __launch_bounds__(256) void rope_table_kernel(
    float* __restrict__ ctab, float* __restrict__ stab)
{
    const int i = blockIdx.x * 256 + threadIdx.x;   // S_*32
    if (i >= S_ * 32) return;
    const int s = i >> 5, p = i & 31;
    const double e = (double)(2 * p) / 64.0;
    const float pf = (float)pow(10000.0, e);
    const float invf = 1.0f / pf;
    const float fr = (float)s * invf;
    ctab[i] = (float)cos((double)fr);
    stab[i] = (float)sin((double)fr);
}

// ---------------------------------------------------------------------------
// Fused flash attention — two-word bf16 MFMA, online softmax, single pass.
// Inputs are PRE-SPLIT hi/lo bf16 planes (qk: [T][2048] rotated q|k;
// vT: [bh][64][512]) so the loop does pure 16B vector staging.
// Grid (bh=64, qt=16), 256 thr = 4 waves; wave w owns kv/d chunk w*16..+15.
// ---------------------------------------------------------------------------
__global__ __launch_bounds__(256, 4) void attn_fused_kernel(
    const ushort_t* __restrict__ qkh, const ushort_t* __restrict__ qkl,
    const ushort_t* __restrict__ vTh, const ushort_t* __restrict__ vTl,
    ushort_t* __restrict__ aoh, ushort_t* __restrict__ aol)
{
    const int bh = blockIdx.x;                 // b*16+h
    const int qt = blockIdx.y;
    const int b = bh >> 4, h = bh & 15;
    const int q0 = qt * 32;
    const int nchunk = (qt >> 1) + 1;

    // bf16 hi/lo tiles, row stride 72 (pad 8) keeps b128 reads 16B-aligned
    __shared__ __align__(16) ushort_t qsh[32 * 72], qsl[32 * 72];  // Q rows (q, d)
    __shared__ __align__(16) ushort_t kvh[64 * 72], kvl[64 * 72];  // K rows, then V^T rows
    __shared__ __align__(16) ushort_t psh[32 * 72], psl[32 * 72];  // P rows (q, kv)
    __shared__ __align__(16) float redm[32][4];      // per-wave row max
    __shared__ __align__(16) float redl[32][4];      // per-wave row sum

    const int tid = threadIdx.x, w = tid >> 6, lane = tid & 63;
    const int lm = lane & 15, lq = lane >> 4;
    const size_t vbase = (size_t)bh * (HD_ * S_);

    // ---- stage Q once: pure 16B copies from planes
    {
        const int row = tid >> 3, g = tid & 7;
        const size_t src = (size_t)(b * S_ + q0 + row) * 2048 + h * HD_ + g * 8;
        *(uint4*)(qsh + row * 72 + g * 8) = *(const uint4*)(qkh + src);
        *(uint4*)(qsl + row * 72 + g * 8) = *(const uint4*)(qkl + src);
    }

    // running state: rows q = i*16 + lq*4 + r, col d = w*16 + lm
    float mrun[2][4], lrun[2][4];
    floatx4 oacc[2] = {};
#pragma unroll
    for (int i = 0; i < 2; i++)
#pragma unroll
        for (int r = 0; r < 4; r++) { mrun[i][r] = -INFINITY; lrun[i][r] = 0.f; }

    for (int c = 0; c < nchunk; c++) {
        const int c0 = c * 64;

        // ---- stage K chunk: 16B copies from planes into shared K/V buffer
#pragma unroll
        for (int it = 0; it < 2; it++) {
            const int i = tid + it * 256;
            const int row = i >> 3, g = i & 7;
            const size_t src = (size_t)(b * S_ + c0 + row) * 2048 + 1024 + h * HD_ + g * 8;
            *(uint4*)(kvh + row * 72 + g * 8) = *(const uint4*)(qkh + src);
            *(uint4*)(kvl + row * 72 + g * 8) = *(const uint4*)(qkl + src);
        }
        // ---- prefetch V^T rows into registers; latency hides under QK
        uint4 vrh[2], vrl[2];
#pragma unroll
        for (int it = 0; it < 2; it++) {
            const int i = tid + it * 256;
            const int row = i >> 3, g = i & 7;     // row = d (0..63)
            const size_t src = vbase + (size_t)row * S_ + c0 + g * 8;
            vrh[it] = *(const uint4*)(vTh + src);
            vrl[it] = *(const uint4*)(vTl + src);
        }
        __syncthreads();   // K (and Q on first iter) visible

        // ---- scores: wave w -> S[32 q][16 kv] chunk; 3 MFMAs per product
        floatx4 acc[2] = {};
#pragma unroll
        for (int k0 = 0; k0 < 64; k0 += 32) {
            const bf16x8 bh16 = *(const bf16x8*)(kvh + (w * 16 + lm) * 72 + k0 + lq * 8);
            const bf16x8 bl16 = *(const bf16x8*)(kvl + (w * 16 + lm) * 72 + k0 + lq * 8);
#pragma unroll
            for (int i = 0; i < 2; i++) {
                const bf16x8 ah = *(const bf16x8*)(qsh + (i * 16 + lm) * 72 + k0 + lq * 8);
                const bf16x8 al = *(const bf16x8*)(qsl + (i * 16 + lm) * 72 + k0 + lq * 8);
                acc[i] = __builtin_amdgcn_mfma_f32_16x16x32_bf16(ah, bh16, acc[i], 0, 0, 0);
                acc[i] = __builtin_amdgcn_mfma_f32_16x16x32_bf16(al, bh16, acc[i], 0, 0, 0);
                acc[i] = __builtin_amdgcn_mfma_f32_16x16x32_bf16(ah, bl16, acc[i], 0, 0, 0);
            }
        }

        // ---- mask + scale, per-row max over this wave's 16 kv
        float sv[2][4];
        const int kvg = c0 + w * 16 + lm;
#pragma unroll
        for (int i = 0; i < 2; i++)
#pragma unroll
            for (int r = 0; r < 4; r++) {
                const int qg = q0 + i * 16 + lq * 4 + r;
                float v = (kvg <= qg) ? acc[i][r] * 0.125f : -INFINITY;
                sv[i][r] = v;
#pragma unroll
                for (int off = 1; off < 16; off <<= 1) v = fmaxf(v, __shfl_xor(v, off));
                if (lm == 0) redm[i * 16 + lq * 4 + r][w] = v;
            }
        __syncthreads();   // redm complete; all K reads done

        // ---- stage V^T from registers (overwrites K) — vector stores
#pragma unroll
        for (int it = 0; it < 2; it++) {
            const int i = tid + it * 256;
            const int row = i >> 3, g = i & 7;
            *(uint4*)(kvh + row * 72 + g * 8) = vrh[it];
            *(uint4*)(kvl + row * 72 + g * 8) = vrl[it];
        }

        // ---- online softmax: new row max, p = exp(s - m'), rescale factor
        float sclr[2][4];
#pragma unroll
        for (int i = 0; i < 2; i++)
#pragma unroll
            for (int r = 0; r < 4; r++) {
                const int q = i * 16 + lq * 4 + r;
                const float4 m4 = *(const float4*)&redm[q][0];
                const float Mc = fmaxf(fmaxf(m4.x, m4.y), fmaxf(m4.z, m4.w));
                const float Mn = fmaxf(mrun[i][r], Mc);
                const float p = expf(sv[i][r] - Mn);
                ushort_t ph, pl;
                split2(p, ph, pl);
                psh[q * 72 + w * 16 + lm] = ph;
                psl[q * 72 + w * 16 + lm] = pl;
                float sum = p;
#pragma unroll
                for (int off = 1; off < 16; off <<= 1) sum += __shfl_xor(sum, off);
                if (lm == 0) redl[q][w] = sum;
                sclr[i][r] = expf(mrun[i][r] - Mn);   // 0 on first chunk
                mrun[i][r] = Mn;
            }
        __syncthreads();   // ps, V^T, redl ready

        // ---- update l, rescale O
#pragma unroll
        for (int i = 0; i < 2; i++)
#pragma unroll
            for (int r = 0; r < 4; r++) {
                const int q = i * 16 + lq * 4 + r;
                const float4 l4 = *(const float4*)&redl[q][0];
                const float lc = l4.x + l4.y + l4.z + l4.w;
                lrun[i][r] = lrun[i][r] * sclr[i][r] + lc;
                oacc[i][r] *= sclr[i][r];
            }

        // ---- PV: O[32 q][16 d chunk w] += (Ph+Pl) · (Vh+Vl)^T
#pragma unroll
        for (int k0 = 0; k0 < 64; k0 += 32) {
            const bf16x8 bh16 = *(const bf16x8*)(kvh + (w * 16 + lm) * 72 + k0 + lq * 8);
            const bf16x8 bl16 = *(const bf16x8*)(kvl + (w * 16 + lm) * 72 + k0 + lq * 8);
#pragma unroll
            for (int i = 0; i < 2; i++) {
                const bf16x8 ah = *(const bf16x8*)(psh + (i * 16 + lm) * 72 + k0 + lq * 8);
                const bf16x8 al = *(const bf16x8*)(psl + (i * 16 + lm) * 72 + k0 + lq * 8);
                oacc[i] = __builtin_amdgcn_mfma_f32_16x16x32_bf16(ah, bh16, oacc[i], 0, 0, 0);
                oacc[i] = __builtin_amdgcn_mfma_f32_16x16x32_bf16(al, bh16, oacc[i], 0, 0, 0);
                oacc[i] = __builtin_amdgcn_mfma_f32_16x16x32_bf16(ah, bl16, oacc[i], 0, 0, 0);
            }
        }
        __syncthreads();   // PV reads done before next chunk overwrites kv/ps
    }

    // ---- epilogue: normalize and emit hi/lo bf16 planes
    const int col = h * HD_ + w * 16 + lm;
#pragma unroll
    for (int i = 0; i < 2; i++)
#pragma unroll
        for (int r = 0; r < 4; r++) {
            const int q = i * 16 + lq * 4 + r;
            const int t = b * S_ + q0 + q;
            const float v = oacc[i][r] / lrun[i][r];
            ushort_t hh, ll;
            split2(v, hh, ll);
            aoh[(size_t)t * D_ + col] = hh;
            aol[(size_t)t * D_ + col] = ll;
        }
}

// ---------------------------------------------------------------------------
// Gating + routing. bf16-rounded logits, top-2 lowest-index tie-break.
// ---------------------------------------------------------------------------
__global__ __launch_bounds__(64) void gate_kernel(
    const ushort_t* __restrict__ xn2, const float* __restrict__ gate_w,
    int* __restrict__ cnt, int* __restrict__ tok, float* __restrict__ wt,
    float* __restrict__ probs)
{
    const int t = blockIdx.x;
    const int lane = threadIdx.x;
    float acc[8] = {0, 0, 0, 0, 0, 0, 0, 0};
    for (int d = lane; d < D_; d += 64) {
        const float xv = bf2f(xn2[(size_t)t * D_ + d]);
        const float4 g0 = ((const float4*)(gate_w + d * 8))[0];
        const float4 g1 = ((const float4*)(gate_w + d * 8))[1];
        acc[0] = fmaf(xv, bf2f(f2bf(g0.x)), acc[0]);
        acc[1] = fmaf(xv, bf2f(f2bf(g0.y)), acc[1]);
        acc[2] = fmaf(xv, bf2f(f2bf(g0.z)), acc[2]);
        acc[3] = fmaf(xv, bf2f(f2bf(g0.w)), acc[3]);
        acc[4] = fmaf(xv, bf2f(f2bf(g1.x)), acc[4]);
        acc[5] = fmaf(xv, bf2f(f2bf(g1.y)), acc[5]);
        acc[6] = fmaf(xv, bf2f(f2bf(g1.z)), acc[6]);
        acc[7] = fmaf(xv, bf2f(f2bf(g1.w)), acc[7]);
    }
#pragma unroll
    for (int e = 0; e < 8; e++) {
#pragma unroll
        for (int off = 32; off; off >>= 1) acc[e] += __shfl_xor(acc[e], off);
        acc[e] = bf2f(f2bf(acc[e]));   // bf16 result of the bf16 matmul
    }

    if (lane == 0) {
        int i1 = 0;
        for (int e = 1; e < 8; e++) if (acc[e] > acc[i1]) i1 = e;
        int i2 = (i1 == 0) ? 1 : 0;
        for (int e = 0; e < 8; e++) if (e != i1 && acc[e] > acc[i2]) i2 = e;
        const float e2 = expf(acc[i2] - acc[i1]);
        const float w1 = 1.f / (1.f + e2);
        const float w2 = e2 * w1;
        const int p1 = atomicAdd(&cnt[i1], 1);
        tok[i1 * T_ + p1] = t; wt[i1 * T_ + p1] = w1;
        const int p2 = atomicAdd(&cnt[i2], 1);
        tok[i2 * T_ + p2] = t; wt[i2 * T_ + p2] = w2;
        const float mx = acc[i1];
        float se = 0.f, pe[8];
        for (int e = 0; e < 8; e++) { pe[e] = expf(acc[e] - mx); se += pe[e]; }
        const float inv = 1.f / se;
        for (int e = 0; e < 8; e++) probs[t * 8 + e] = pe[e] * inv;
    }
}

__global__ void zero_route_kernel(int* __restrict__ cnt)
{
    if (threadIdx.x < 8) cnt[threadIdx.x] = 0;
}

// ---------------------------------------------------------------------------
// dist = probs.mean(0); lb = E * sum(dist^2); writes out tail.
// ---------------------------------------------------------------------------
__global__ __launch_bounds__(256) void reduce_dist_kernel(
    const float* __restrict__ probs, float* __restrict__ out)
{
    __shared__ float part[256];
    __shared__ float dist8[8];
    const int tid = threadIdx.x;
    const int e = tid & 7, chunk = tid >> 3;   // 32 chunks
    float s = 0.f;
    for (int t = chunk; t < T_; t += 32) s += probs[t * 8 + e];
    part[tid] = s;
    __syncthreads();
    if (tid < 8) {
        float tot = 0.f;
        for (int c = 0; c < 32; c++) tot += part[c * 8 + tid];
        const float dv = tot * (1.0f / T_);
        dist8[tid] = dv;
        out[(size_t)T_ * D_ + 1 + tid] = dv;
    }
    __syncthreads();
    if (tid == 0) {
        float s2 = 0.f;
        for (int k = 0; k < 8; k++) s2 += dist8[k] * dist8[k];
        out[(size_t)T_ * D_] = (float)E_ * s2;
    }
}

// ---------------------------------------------------------------------------
// Launch
// ---------------------------------------------------------------------------
extern "C" void kernel_launch(void* const* d_in, const int* in_sizes, int n_in,
                              void* d_out, int out_size, void* d_ws, size_t ws_size,
                              hipStream_t stream)
{
    const float* x      = (const float*)d_in[0];
    const float* ln1_g  = (const float*)d_in[1];
    const float* ln1_b  = (const float*)d_in[2];
    const float* ln2_g  = (const float*)d_in[3];
    const float* ln2_b  = (const float*)d_in[4];
    const float* w_qkv  = (const float*)d_in[5];
    const float* w_o    = (const float*)d_in[6];
    const float* gate_w = (const float*)d_in[7];
    const float* w_gate = (const float*)d_in[8];
    const float* w_up   = (const float*)d_in[9];
    const float* w_down = (const float*)d_in[10];
    float* out = (float*)d_out;

    char* ws = (char*)d_ws;
    size_t off = 0;
    auto alloc = [&](size_t bytes) { size_t o = off; off += (bytes + 255) & ~(size_t)255; return o; };
    // persistent-through-MoE region
    ushort_t* wguT  = (ushort_t*)(ws + alloc((size_t)E_ * GU_ * D_ * 2));   // 58.7 MB
    ushort_t* wdT   = (ushort_t*)(ws + alloc((size_t)E_ * D_ * HID_ * 2));  // 29.4 MB
    ushort_t* xnh   = (ushort_t*)(ws + alloc((size_t)T_ * D_ * 4));         // hi+lo planes
    ushort_t* xnl   = xnh + (size_t)T_ * D_;
    ushort_t* xn2   = (ushort_t*)(ws + alloc((size_t)T_ * D_ * 2));
    int*      cnt   = (int*)     (ws + alloc(64));
    int*      tok   = (int*)     (ws + alloc((size_t)E_ * T_ * 4));
    float*    wt    = (float*)   (ws + alloc((size_t)E_ * T_ * 4));
    float*    probs = (float*)   (ws + alloc((size_t)T_ * E_ * 4));
    float*    ctab  = (float*)   (ws + alloc((size_t)S_ * 32 * 4));
    float*    stab  = (float*)   (ws + alloc((size_t)S_ * 32 * 4));
    // scratch union (59 MB, aliased by lifetime):
    //   A (QKV GEMM):  wqkvT hi/lo [0,12.58M) read; qkh/qkl [12.58M,29.36M)
    //                  + vT hi/lo [29.36M,37.75M) written by fused epilogue
    //   B (attn):      qkh/qkl/vT read; aoh/aol [37.75M,46.14M) written
    //   C (W_O):       x1 [0,8.39M) + woT [8.39M,12.58M) (wqkvT dead);
    //                  aoh/aol read
    //   D (MoE):       Hc [0,58.7M) (everything else dead)
    const size_t scratch0 = alloc((size_t)59 << 20);
    char* sc = ws + scratch0;
    ushort_t* wqkvTh= (ushort_t*)(sc);
    ushort_t* wqkvTl= wqkvTh + (size_t)D3_ * D_;                  // ends 12,582,912
    ushort_t* qkh   = (ushort_t*)(sc + 12582912);
    ushort_t* qkl   = qkh + (size_t)T_ * 2048;                    // ends 29,360,128
    ushort_t* vTh   = (ushort_t*)(sc + 29360128);
    ushort_t* vTl   = vTh + (size_t)64 * HD_ * S_;                // ends 37,748,736
    ushort_t* aoh   = (ushort_t*)(sc + 37748736);
    ushort_t* aol   = aoh + (size_t)T_ * D_;                      // ends 46,137,344
    float*    x1    = (float*)   (sc);                            // W_O phase
    ushort_t* woTh  = (ushort_t*)(sc + 8388608);
    ushort_t* woTl  = woTh + (size_t)D_ * D_;
    ushort_t* Hc    = (ushort_t*)(sc);                            // MoE phase
    (void)ws_size; (void)in_sizes; (void)n_in; (void)out_size;

    // weight transposes -> bf16 (N x K); gate/up interleaved into wguT
    hipLaunchKernelGGL(transpose_bf16_kernel, dim3(HID_ / 32, D_ / 32, E_), dim3(256), 0, stream,
                       w_gate, wguT, D_, HID_, 2, 0, (long)GU_ * D_);
    hipLaunchKernelGGL(transpose_bf16_kernel, dim3(HID_ / 32, D_ / 32, E_), dim3(256), 0, stream,
                       w_up, wguT, D_, HID_, 2, 1, (long)GU_ * D_);
    hipLaunchKernelGGL(transpose_bf16_kernel, dim3(D_ / 32, HID_ / 32, E_), dim3(256), 0, stream,
                       w_down, wdT, HID_, D_, 1, 0, (long)D_ * HID_);

    // w_qkv (D x 3D) -> hi/lo bf16 planes (3D x D)
    hipLaunchKernelGGL(transpose_split_kernel, dim3(D3_ / 32, D_ / 32), dim3(256), 0, stream,
                       w_qkv, wqkvTh, wqkvTl, D_, D3_);

    // RoPE tables
    hipLaunchKernelGGL(rope_table_kernel, dim3((S_ * 32 + 255) / 256), dim3(256), 0, stream,
                       ctab, stab);

    // LN1 -> hi/lo bf16 planes
    hipLaunchKernelGGL(ln_kernel, dim3(T_), dim3(256), 0, stream,
                       x, ln1_g, ln1_b, (ushort_t*)nullptr, xnh, xnl);

    // QKV GEMM with fused RoPE+split+V-transpose epilogue: grid (24,16)
    hipLaunchKernelGGL(qkv_rope_gemm_kernel, dim3(D3_ / 128, T_ / 128), dim3(256), 0, stream,
                       xnh, xnl, wqkvTh, wqkvTl, ctab, stab, qkh, qkl, vTh, vTl);

    // fused flash attention -> attn output hi/lo planes
    hipLaunchKernelGGL(attn_fused_kernel, dim3(64, 16), dim3(256), 0, stream,
                       qkh, qkl, vTh, vTl, aoh, aol);

    // w_o (D x D) -> hi/lo bf16 planes (wqkvT dead now)
    hipLaunchKernelGGL(transpose_split_kernel, dim3(D_ / 32, D_ / 32), dim3(256), 0, stream,
                       w_o, woTh, woTl, D_, D_);

    // W_O two-word bf16 MFMA GEMM + residual -> x1 AND out
    hipLaunchKernelGGL(gemm2w_kernel, dim3(D_ / 128, T_ / 128), dim3(256), 0, stream,
                       aoh, aol, woTh, woTl, x, x1, out, D_);

    // LN2 (bf16)
    hipLaunchKernelGGL(ln_kernel, dim3(T_), dim3(256), 0, stream,
                       x1, ln2_g, ln2_b, xn2, (ushort_t*)nullptr, (ushort_t*)nullptr);

    // gating + routing + aux outputs
    hipLaunchKernelGGL(zero_route_kernel, dim3(1), dim3(64), 0, stream, cnt);
    hipLaunchKernelGGL(gate_kernel, dim3(T_), dim3(64), 0, stream,
                       xn2, gate_w, cnt, tok, wt, probs);
    hipLaunchKernelGGL(reduce_dist_kernel, dim3(1), dim3(256), 0, stream, probs, out);

    // MoE routed: fused gate+up (+silu), then weighted down (split-K=2)
    hipLaunchKernelGGL(gateup_idx_kernel, dim3(GU_ / 128, T_ / 128, E_), dim3(256), 0, stream,
                       xn2, wguT, cnt, tok, Hc);
    hipLaunchKernelGGL(down_idx_kernel, dim3(D_ / 128, T_ / 128, E_ * 2), dim3(256), 0, stream,
                       Hc, wdT, cnt, tok, wt, out);
}

// Round 9
// 622.049 us; speedup vs baseline: 1.0139x; 1.0139x over previous
//
#include <hip/hip_runtime.h>
#include <hip/hip_bf16.h>
#include <math.h>

// ---------------------------------------------------------------------------
// Shapes (fixed by the problem)
// ---------------------------------------------------------------------------
#define B_    4
#define S_    512
#define D_    1024
#define T_    2048          // B*S tokens
#define H_    16
#define HD_   64
#define E_    8
#define HID_  1792
#define D3_   3072
#define GU_   (2 * HID_)    // 3584 interleaved gate/up columns

typedef unsigned short ushort_t;
typedef __bf16 bf16x8 __attribute__((ext_vector_type(8)));
typedef float  floatx4 __attribute__((ext_vector_type(4)));

__device__ inline float bf2f(ushort_t u) {
    return __uint_as_float(((unsigned)u) << 16);
}
__device__ inline ushort_t f2bf(float f) {
    __hip_bfloat16 h = __float2bfloat16(f);
    return __builtin_bit_cast(ushort_t, h);
}

// two-word bf16 split: x ~= hi + lo with combined rel error ~2^-17.
// hi = truncated-bf16(x) (exact prefix), lo = rne-bf16(x - hi).
__device__ __forceinline__ void split2(float x, ushort_t& h, ushort_t& l) {
    const unsigned ub = __float_as_uint(x);
    h = (ushort_t)(ub >> 16);
    l = f2bf(x - __uint_as_float(ub & 0xFFFF0000u));
}

// async 16B/lane global->LDS; lds dest wave-uniform base (+lane*16 by HW)
__device__ __forceinline__ void gl2lds16(const ushort_t* g, ushort_t* l) {
    __builtin_amdgcn_global_load_lds(
        (const __attribute__((address_space(1))) void*)g,
        (__attribute__((address_space(3))) void*)l, 16, 0, 0);
}

// ---------------------------------------------------------------------------
// Vectorized transpose + fp32->bf16: in (z,R,C) f32 ->
// out[z*outEstride + (c*mul+add)*R + r]. 64x64 tiles, float4 loads (16B/lane),
// packed 8-ushort stores (16B/lane, contiguous along r). Bit-identical values.
// ---------------------------------------------------------------------------
__global__ __launch_bounds__(256) void transpose_bf16_kernel(
    const float* __restrict__ in, ushort_t* __restrict__ out,
    int R, int C, int mul, int add, long outEstride)
{
    __shared__ float tile[64][65];
    const int bx = blockIdx.x * 64;           // c
    const int by = blockIdx.y * 64;           // r
    const size_t iofs = (size_t)blockIdx.z * R * C;
    const size_t oofs = (size_t)blockIdx.z * outEstride;
    const int tid = threadIdx.x;
    const int lr = tid >> 4;                  // 0..15
    const int lc4 = (tid & 15) * 4;           // 0..60
#pragma unroll
    for (int i = 0; i < 4; i++) {
        const int r = lr + i * 16;
        const float4 v = *(const float4*)(in + iofs + (size_t)(by + r) * C + bx + lc4);
        tile[r][lc4 + 0] = v.x;
        tile[r][lc4 + 1] = v.y;
        tile[r][lc4 + 2] = v.z;
        tile[r][lc4 + 3] = v.w;
    }
    __syncthreads();
    const int sc = tid >> 3;                  // 0..31
    const int rg = (tid & 7) * 8;             // 0..56
#pragma unroll
    for (int i = 0; i < 2; i++) {
        const int c = sc + i * 32;
        ushort4 o0, o1;
        o0.x = f2bf(tile[rg + 0][c]); o0.y = f2bf(tile[rg + 1][c]);
        o0.z = f2bf(tile[rg + 2][c]); o0.w = f2bf(tile[rg + 3][c]);
        o1.x = f2bf(tile[rg + 4][c]); o1.y = f2bf(tile[rg + 5][c]);
        o1.z = f2bf(tile[rg + 6][c]); o1.w = f2bf(tile[rg + 7][c]);
        ushort_t* op = out + oofs + (size_t)((bx + c) * mul + add) * R + by + rg;
        *(ushort4*)(op)     = o0;
        *(ushort4*)(op + 4) = o1;
    }
}

// ---------------------------------------------------------------------------
// Vectorized transpose + fp32 -> two-word bf16 planes (same access pattern).
// ---------------------------------------------------------------------------
__global__ __launch_bounds__(256) void transpose_split_kernel(
    const float* __restrict__ in, ushort_t* __restrict__ outh,
    ushort_t* __restrict__ outl, int R, int C)
{
    __shared__ float tile[64][65];
    const int bx = blockIdx.x * 64;           // c
    const int by = blockIdx.y * 64;           // r
    const int tid = threadIdx.x;
    const int lr = tid >> 4;
    const int lc4 = (tid & 15) * 4;
#pragma unroll
    for (int i = 0; i < 4; i++) {
        const int r = lr + i * 16;
        const float4 v = *(const float4*)(in + (size_t)(by + r) * C + bx + lc4);
        tile[r][lc4 + 0] = v.x;
        tile[r][lc4 + 1] = v.y;
        tile[r][lc4 + 2] = v.z;
        tile[r][lc4 + 3] = v.w;
    }
    __syncthreads();
    const int sc = tid >> 3;
    const int rg = (tid & 7) * 8;
#pragma unroll
    for (int i = 0; i < 2; i++) {
        const int c = sc + i * 32;
        ushort4 h0, l0, h1, l1;
        split2(tile[rg + 0][c], h0.x, l0.x); split2(tile[rg + 1][c], h0.y, l0.y);
        split2(tile[rg + 2][c], h0.z, l0.z); split2(tile[rg + 3][c], h0.w, l0.w);
        split2(tile[rg + 4][c], h1.x, l1.x); split2(tile[rg + 5][c], h1.y, l1.y);
        split2(tile[rg + 6][c], h1.z, l1.z); split2(tile[rg + 7][c], h1.w, l1.w);
        const size_t ob = (size_t)(bx + c) * R + by + rg;
        *(ushort4*)(outh + ob)     = h0;
        *(ushort4*)(outh + ob + 4) = h1;
        *(ushort4*)(outl + ob)     = l0;
        *(ushort4*)(outl + ob + 4) = l1;
    }
}

// ---------------------------------------------------------------------------
// LayerNorm: x (rows x 1024) f32 -> optional bf16 out and/or hi/lo planes.
// Optional FUSED GATING (gate_w != null): wave 0 replays the exact
// gate_kernel loop (same per-lane d-stride, fmaf order, shfl tree, bf16
// rounding) reading the bf16 row from LDS -> bitwise-identical logits.
// ---------------------------------------------------------------------------
__global__ __launch_bounds__(256) void ln_kernel(
    const float* __restrict__ x, const float* __restrict__ g,
    const float* __restrict__ b, ushort_t* __restrict__ outb,
    ushort_t* __restrict__ outh, ushort_t* __restrict__ outl,
    const float* __restrict__ gate_w, int* __restrict__ cnt,
    int* __restrict__ tok, float* __restrict__ wt,
    float* __restrict__ probs)
{
    const int t = blockIdx.x;
    const int tid = threadIdx.x;
    const int wave = tid >> 6, lane = tid & 63;
    const float4 v = ((const float4*)(x + (size_t)t * D_))[tid];

    float s = v.x + v.y + v.z + v.w;
#pragma unroll
    for (int off = 32; off; off >>= 1) s += __shfl_xor(s, off);
    __shared__ float red1[4];
    __shared__ float red2[4];
    __shared__ ushort_t xb[1024];
    if (lane == 0) red1[wave] = s;
    __syncthreads();
    const float mu = (red1[0] + red1[1] + red1[2] + red1[3]) * (1.0f / D_);

    const float dx = v.x - mu, dy = v.y - mu, dz = v.z - mu, dw = v.w - mu;
    float vs = dx * dx + dy * dy + dz * dz + dw * dw;
#pragma unroll
    for (int off = 32; off; off >>= 1) vs += __shfl_xor(vs, off);
    if (lane == 0) red2[wave] = vs;
    __syncthreads();
    const float var = (red2[0] + red2[1] + red2[2] + red2[3]) * (1.0f / D_);
    const float rs = 1.0f / sqrtf(var + 1e-5f);

    const float4 gg = ((const float4*)g)[tid];
    const float4 bb = ((const float4*)b)[tid];
    float4 o;
    o.x = dx * rs * gg.x + bb.x;
    o.y = dy * rs * gg.y + bb.y;
    o.z = dz * rs * gg.z + bb.z;
    o.w = dw * rs * gg.w + bb.w;
    ushort4 ob;
    ob.x = f2bf(o.x); ob.y = f2bf(o.y); ob.z = f2bf(o.z); ob.w = f2bf(o.w);
    if (outb) ((ushort4*)(outb + (size_t)t * D_))[tid] = ob;
    if (outh) {
        ushort4 oh, ol;
        split2(o.x, oh.x, ol.x); split2(o.y, oh.y, ol.y);
        split2(o.z, oh.z, ol.z); split2(o.w, oh.w, ol.w);
        ((ushort4*)(outh + (size_t)t * D_))[tid] = oh;
        ((ushort4*)(outl + (size_t)t * D_))[tid] = ol;
    }

    if (gate_w) {
        *(ushort4*)(xb + tid * 4) = ob;
        __syncthreads();
        if (tid < 64) {
            float acc[8] = {0, 0, 0, 0, 0, 0, 0, 0};
            for (int d = tid; d < D_; d += 64) {
                const float xv = bf2f(xb[d]);
                const float4 g0 = ((const float4*)(gate_w + d * 8))[0];
                const float4 g1 = ((const float4*)(gate_w + d * 8))[1];
                acc[0] = fmaf(xv, bf2f(f2bf(g0.x)), acc[0]);
                acc[1] = fmaf(xv, bf2f(f2bf(g0.y)), acc[1]);
                acc[2] = fmaf(xv, bf2f(f2bf(g0.z)), acc[2]);
                acc[3] = fmaf(xv, bf2f(f2bf(g0.w)), acc[3]);
                acc[4] = fmaf(xv, bf2f(f2bf(g1.x)), acc[4]);
                acc[5] = fmaf(xv, bf2f(f2bf(g1.y)), acc[5]);
                acc[6] = fmaf(xv, bf2f(f2bf(g1.z)), acc[6]);
                acc[7] = fmaf(xv, bf2f(f2bf(g1.w)), acc[7]);
            }
#pragma unroll
            for (int e = 0; e < 8; e++) {
#pragma unroll
                for (int off = 32; off; off >>= 1) acc[e] += __shfl_xor(acc[e], off);
                acc[e] = bf2f(f2bf(acc[e]));   // bf16 result of the bf16 matmul
            }
            if (tid == 0) {
                int i1 = 0;
                for (int e = 1; e < 8; e++) if (acc[e] > acc[i1]) i1 = e;
                int i2 = (i1 == 0) ? 1 : 0;
                for (int e = 0; e < 8; e++) if (e != i1 && acc[e] > acc[i2]) i2 = e;
                const float e2 = expf(acc[i2] - acc[i1]);
                const float w1 = 1.f / (1.f + e2);
                const float w2 = e2 * w1;
                const int p1 = atomicAdd(&cnt[i1], 1);
                tok[i1 * T_ + p1] = t; wt[i1 * T_ + p1] = w1;
                const int p2 = atomicAdd(&cnt[i2], 1);
                tok[i2 * T_ + p2] = t; wt[i2 * T_ + p2] = w2;
                const float mx = acc[i1];
                float se = 0.f, pe[8];
                for (int e = 0; e < 8; e++) { pe[e] = expf(acc[e] - mx); se += pe[e]; }
                const float inv = 1.f / se;
                for (int e = 0; e < 8; e++) probs[t * 8 + e] = pe[e] * inv;
            }
        }
    }
}

// ---------------------------------------------------------------------------
// Two-word bf16 MFMA GEMM: C[M x ncols] = (Ah+Al)[M x 1024] · (Bh+Bl)[N x 1024]^T
// (+ optional f32 residual, optional second output). 128x128 tile, BK=32,
// 4 waves, 4x4 16x16x32 MFMAs per wave, 3 per product (hh + lh + hl).
// ---------------------------------------------------------------------------
__global__ __launch_bounds__(256) void gemm2w_kernel(
    const ushort_t* __restrict__ Ah, const ushort_t* __restrict__ Al,
    const ushort_t* __restrict__ Bh, const ushort_t* __restrict__ Bl,
    const float* __restrict__ res, float* __restrict__ C,
    float* __restrict__ C2, int ncols)
{
    const int row0 = blockIdx.y * 128, col0 = blockIdx.x * 128;

    __shared__ __align__(16) ushort_t Ash[128 * 32], Asl[128 * 32];
    __shared__ __align__(16) ushort_t Bsh[128 * 32], Bsl[128 * 32];
    const int tid = threadIdx.x, w = tid >> 6, lane = tid & 63;
    const int lr = lane >> 2, lc = (lane & 3) * 8;
    const int wm = (w >> 1) * 64, wn = (w & 1) * 64;
    const int lm = lane & 15, lq = lane >> 4;

    floatx4 acc[4][4] = {};

    const ushort_t* Aph = Ah + (size_t)(row0 + w * 16 + lr) * D_ + lc;
    const ushort_t* Apl = Al + (size_t)(row0 + w * 16 + lr) * D_ + lc;
    const ushort_t* Bph = Bh + (size_t)(col0 + w * 16 + lr) * D_ + lc;
    const ushort_t* Bpl = Bl + (size_t)(col0 + w * 16 + lr) * D_ + lc;
    ushort_t* lAh = Ash + w * 512;
    ushort_t* lAl = Asl + w * 512;
    ushort_t* lBh = Bsh + w * 512;
    ushort_t* lBl = Bsl + w * 512;

    for (int k0 = 0; k0 < D_; k0 += 32) {
        __syncthreads();
        gl2lds16(Aph + k0, lAh);
        gl2lds16(Aph + k0 + (size_t)64 * D_, lAh + 2048);
        gl2lds16(Apl + k0, lAl);
        gl2lds16(Apl + k0 + (size_t)64 * D_, lAl + 2048);
        gl2lds16(Bph + k0, lBh);
        gl2lds16(Bph + k0 + (size_t)64 * D_, lBh + 2048);
        gl2lds16(Bpl + k0, lBl);
        gl2lds16(Bpl + k0 + (size_t)64 * D_, lBl + 2048);
        __syncthreads();
        bf16x8 ah[4], al[4], bh16[4], bl16[4];
#pragma unroll
        for (int i = 0; i < 4; i++) {
            ah[i] = *(const bf16x8*)(Ash + (wm + i * 16 + lm) * 32 + lq * 8);
            al[i] = *(const bf16x8*)(Asl + (wm + i * 16 + lm) * 32 + lq * 8);
        }
#pragma unroll
        for (int j = 0; j < 4; j++) {
            bh16[j] = *(const bf16x8*)(Bsh + (wn + j * 16 + lm) * 32 + lq * 8);
            bl16[j] = *(const bf16x8*)(Bsl + (wn + j * 16 + lm) * 32 + lq * 8);
        }
#pragma unroll
        for (int i = 0; i < 4; i++)
#pragma unroll
            for (int j = 0; j < 4; j++) {
                acc[i][j] = __builtin_amdgcn_mfma_f32_16x16x32_bf16(ah[i], bh16[j], acc[i][j], 0, 0, 0);
                acc[i][j] = __builtin_amdgcn_mfma_f32_16x16x32_bf16(al[i], bh16[j], acc[i][j], 0, 0, 0);
                acc[i][j] = __builtin_amdgcn_mfma_f32_16x16x32_bf16(ah[i], bl16[j], acc[i][j], 0, 0, 0);
            }
    }

#pragma unroll
    for (int i = 0; i < 4; i++)
#pragma unroll
        for (int r = 0; r < 4; r++) {
            const int row = row0 + wm + i * 16 + lq * 4 + r;
#pragma unroll
            for (int j = 0; j < 4; j++) {
                const int col = col0 + wn + j * 16 + lm;
                const size_t idx = (size_t)row * ncols + col;
                float o = acc[i][j][r];
                if (res) o += res[idx];
                C[idx] = o;
                if (C2) C2[idx] = o;
            }
        }
}

// ---------------------------------------------------------------------------
// QKV GEMM with fused RoPE + two-word split + V-transpose epilogue.
// ---------------------------------------------------------------------------
__global__ __launch_bounds__(256) void qkv_rope_gemm_kernel(
    const ushort_t* __restrict__ Ah, const ushort_t* __restrict__ Al,
    const ushort_t* __restrict__ Bh, const ushort_t* __restrict__ Bl,
    const float* __restrict__ ctab, const float* __restrict__ stab,
    ushort_t* __restrict__ qkh, ushort_t* __restrict__ qkl,
    ushort_t* __restrict__ vTh, ushort_t* __restrict__ vTl)
{
    const int row0 = blockIdx.y * 128, col0 = blockIdx.x * 128;

    __shared__ __align__(16) ushort_t Ash[128 * 32], Asl[128 * 32];
    __shared__ __align__(16) ushort_t Bsh[128 * 32], Bsl[128 * 32];
    const int tid = threadIdx.x, w = tid >> 6, lane = tid & 63;
    const int lr = lane >> 2, lc = (lane & 3) * 8;
    const int wm = (w >> 1) * 64, wn = (w & 1) * 64;
    const int lm = lane & 15, lq = lane >> 4;

    floatx4 acc[4][4] = {};

    const ushort_t* Aph = Ah + (size_t)(row0 + w * 16 + lr) * D_ + lc;
    const ushort_t* Apl = Al + (size_t)(row0 + w * 16 + lr) * D_ + lc;
    const ushort_t* Bph = Bh + (size_t)(col0 + w * 16 + lr) * D_ + lc;
    const ushort_t* Bpl = Bl + (size_t)(col0 + w * 16 + lr) * D_ + lc;
    ushort_t* lAh = Ash + w * 512;
    ushort_t* lAl = Asl + w * 512;
    ushort_t* lBh = Bsh + w * 512;
    ushort_t* lBl = Bsl + w * 512;

    for (int k0 = 0; k0 < D_; k0 += 32) {
        __syncthreads();
        gl2lds16(Aph + k0, lAh);
        gl2lds16(Aph + k0 + (size_t)64 * D_, lAh + 2048);
        gl2lds16(Apl + k0, lAl);
        gl2lds16(Apl + k0 + (size_t)64 * D_, lAl + 2048);
        gl2lds16(Bph + k0, lBh);
        gl2lds16(Bph + k0 + (size_t)64 * D_, lBh + 2048);
        gl2lds16(Bpl + k0, lBl);
        gl2lds16(Bpl + k0 + (size_t)64 * D_, lBl + 2048);
        __syncthreads();
        bf16x8 ah[4], al[4], bh16[4], bl16[4];
#pragma unroll
        for (int i = 0; i < 4; i++) {
            ah[i] = *(const bf16x8*)(Ash + (wm + i * 16 + lm) * 32 + lq * 8);
            al[i] = *(const bf16x8*)(Asl + (wm + i * 16 + lm) * 32 + lq * 8);
        }
#pragma unroll
        for (int j = 0; j < 4; j++) {
            bh16[j] = *(const bf16x8*)(Bsh + (wn + j * 16 + lm) * 32 + lq * 8);
            bl16[j] = *(const bf16x8*)(Bsl + (wn + j * 16 + lm) * 32 + lq * 8);
        }
#pragma unroll
        for (int i = 0; i < 4; i++)
#pragma unroll
            for (int j = 0; j < 4; j++) {
                acc[i][j] = __builtin_amdgcn_mfma_f32_16x16x32_bf16(ah[i], bh16[j], acc[i][j], 0, 0, 0);
                acc[i][j] = __builtin_amdgcn_mfma_f32_16x16x32_bf16(al[i], bh16[j], acc[i][j], 0, 0, 0);
                acc[i][j] = __builtin_amdgcn_mfma_f32_16x16x32_bf16(ah[i], bl16[j], acc[i][j], 0, 0, 0);
            }
    }

    const bool isV = (col0 >= 2 * D_);   // block-uniform (D3 tiles split at 2048)
#pragma unroll
    for (int i = 0; i < 4; i++)
#pragma unroll
        for (int j = 0; j < 4; j++) {
            const int col = col0 + wn + j * 16 + lm;
#pragma unroll
            for (int r = 0; r < 4; r++) {
                const int row = row0 + wm + i * 16 + lq * 4 + r;   // token t
                float v = acc[i][j][r];
                if (!isV) {
                    // RoPE: partner col = col^1 lives in lane^1 (same i,j,r)
                    const float vp = __shfl_xor(v, 1);
                    const int pair = (col & 63) >> 1;
                    const int s = row & (S_ - 1);
                    const float cc = ctab[s * 32 + pair];
                    const float sn = stab[s * 32 + pair];
                    v = (lm & 1) ? fmaf(vp, sn, v * cc)
                                 : fmaf(-vp, sn, v * cc);
                    ushort_t hh, ll;
                    split2(v, hh, ll);
                    qkh[(size_t)row * 2048 + col] = hh;
                    qkl[(size_t)row * 2048 + col] = ll;
                } else {
                    ushort_t hh, ll;
                    split2(v, hh, ll);
                    const int dg = col - 2 * D_;           // 0..1023
                    const int bh = (row >> 9) * 16 + (dg >> 6);
                    const int d  = dg & 63;
                    const int s  = row & (S_ - 1);
                    vTh[((size_t)bh * 64 + d) * 512 + s] = hh;
                    vTl[((size_t)bh * 64 + d) * 512 + s] = ll;
                }
            }
        }
}

// ---------------------------------------------------------------------------
// Routed fused gate+up MoE GEMM: rows gathered from per-expert token lists.
// Single-buffer 2-barrier staging (proven structure).
// ---------------------------------------------------------------------------
__global__ __launch_bounds__(256) void gateup_idx_kernel(
    const ushort_t* __restrict__ A, const ushort_t* __restrict__ Bgu,
    const int* __restrict__ cnt, const int* __restrict__ tok,
    ushort_t* __restrict__ Hc)
{
    const int e = blockIdx.z;
    const int cntE = cnt[e];
    const int row0 = blockIdx.y * 128;
    if (row0 >= cntE) return;
    const int col0 = blockIdx.x * 128;
    const ushort_t* Bt = Bgu + (size_t)e * GU_ * D_;
    ushort_t* Hp = Hc + (size_t)e * T_ * HID_;

    __shared__ __align__(16) ushort_t As[128 * 32];
    __shared__ __align__(16) ushort_t Bs[128 * 32];
    const int tid = threadIdx.x, w = tid >> 6, lane = tid & 63;
    const int lr = lane >> 2, lc = (lane & 3) * 8;
    const int wm = (w >> 1) * 64, wn = (w & 1) * 64;
    const int lm = lane & 15, lq = lane >> 4;

    floatx4 acc[4][4] = {};

    int r0c = row0 + w * 16 + lr;  if (r0c > cntE - 1) r0c = cntE - 1;
    int r1c = row0 + 64 + w * 16 + lr; if (r1c > cntE - 1) r1c = cntE - 1;
    const ushort_t* Ap0 = A + (size_t)tok[e * T_ + r0c] * D_ + lc;
    const ushort_t* Ap1 = A + (size_t)tok[e * T_ + r1c] * D_ + lc;
    const ushort_t* Bp = Bt + (size_t)(col0 + w * 16 + lr) * D_ + lc;
    ushort_t* lA = As + w * 512;
    ushort_t* lB = Bs + w * 512;

    for (int k0 = 0; k0 < D_; k0 += 32) {
        __syncthreads();
        gl2lds16(Ap0 + k0, lA);
        gl2lds16(Ap1 + k0, lA + 2048);
        gl2lds16(Bp + k0, lB);
        gl2lds16(Bp + k0 + (size_t)64 * D_, lB + 2048);
        __syncthreads();
        bf16x8 a[4], b[4];
#pragma unroll
        for (int i = 0; i < 4; i++)
            a[i] = *(const bf16x8*)(As + (wm + i * 16 + lm) * 32 + lq * 8);
#pragma unroll
        for (int j = 0; j < 4; j++)
            b[j] = *(const bf16x8*)(Bs + (wn + j * 16 + lm) * 32 + lq * 8);
#pragma unroll
        for (int i = 0; i < 4; i++)
#pragma unroll
            for (int j = 0; j < 4; j++)
                acc[i][j] = __builtin_amdgcn_mfma_f32_16x16x32_bf16(a[i], b[j], acc[i][j], 0, 0, 0);
    }

    // epilogue: adjacent lanes hold (gate, up) for the same hidden unit
#pragma unroll
    for (int i = 0; i < 4; i++)
#pragma unroll
        for (int j = 0; j < 4; j++)
#pragma unroll
            for (int r = 0; r < 4; r++) {
                const float v = acc[i][j][r];
                const float vp = __shfl_xor(v, 1);
                const float g = (lm & 1) ? vp : v;
                const float u = (lm & 1) ? v : vp;
                const float h = g / (1.f + __expf(-g)) * u;
                if (!(lm & 1)) {
                    const int row = row0 + wm + i * 16 + lq * 4 + r;
                    const int col = col0 + wn + j * 16 + lm;    // even
                    Hp[(size_t)row * HID_ + (col >> 1)] = f2bf(h);
                }
            }
}

// ---------------------------------------------------------------------------
// Routed MoE down GEMM, split-K: out[tok[r]] += wt[r] * (Hc[e] @ wd[e]^T).
// grid (8, 16, E*2): z -> (expert, k-slice of HID/2). Single-buffer staging.
// ---------------------------------------------------------------------------
__global__ __launch_bounds__(256) void down_idx_kernel(
    const ushort_t* __restrict__ Hc, const ushort_t* __restrict__ Wd,
    const int* __restrict__ cnt, const int* __restrict__ tok,
    const float* __restrict__ wt, float* __restrict__ out)
{
    const int e = blockIdx.z >> 1;
    const int ks = blockIdx.z & 1;
    const int cntE = cnt[e];
    const int row0 = blockIdx.y * 128;
    if (row0 >= cntE) return;
    const int col0 = blockIdx.x * 128;
    const int kBegin = ks * (HID_ / 2);
    const ushort_t* A = Hc + (size_t)e * T_ * HID_;
    const ushort_t* Bt = Wd + (size_t)e * D_ * HID_;

    __shared__ __align__(16) ushort_t As[128 * 32];
    __shared__ __align__(16) ushort_t Bs[128 * 32];
    const int tid = threadIdx.x, w = tid >> 6, lane = tid & 63;
    const int lr = lane >> 2, lc = (lane & 3) * 8;
    const int wm = (w >> 1) * 64, wn = (w & 1) * 64;
    const int lm = lane & 15, lq = lane >> 4;

    floatx4 acc[4][4] = {};

    const ushort_t* Ap = A + (size_t)(row0 + w * 16 + lr) * HID_ + kBegin + lc;
    const ushort_t* Bp = Bt + (size_t)(col0 + w * 16 + lr) * HID_ + kBegin + lc;
    ushort_t* lA = As + w * 512;
    ushort_t* lB = Bs + w * 512;

    for (int k0 = 0; k0 < HID_ / 2; k0 += 32) {
        __syncthreads();
        gl2lds16(Ap + k0, lA);
        gl2lds16(Ap + k0 + (size_t)64 * HID_, lA + 2048);
        gl2lds16(Bp + k0, lB);
        gl2lds16(Bp + k0 + (size_t)64 * HID_, lB + 2048);
        __syncthreads();
        bf16x8 a[4], b[4];
#pragma unroll
        for (int i = 0; i < 4; i++)
            a[i] = *(const bf16x8*)(As + (wm + i * 16 + lm) * 32 + lq * 8);
#pragma unroll
        for (int j = 0; j < 4; j++)
            b[j] = *(const bf16x8*)(Bs + (wn + j * 16 + lm) * 32 + lq * 8);
#pragma unroll
        for (int i = 0; i < 4; i++)
#pragma unroll
            for (int j = 0; j < 4; j++)
                acc[i][j] = __builtin_amdgcn_mfma_f32_16x16x32_bf16(a[i], b[j], acc[i][j], 0, 0, 0);
    }

#pragma unroll
    for (int i = 0; i < 4; i++)
#pragma unroll
        for (int r = 0; r < 4; r++) {
            const int row = row0 + wm + i * 16 + lq * 4 + r;
            if (row < cntE) {
                const int t = tok[e * T_ + row];
                const float scale = wt[e * T_ + row];
#pragma unroll
                for (int j = 0; j < 4; j++) {
                    const int col = col0 + wn + j * 16 + lm;
                    atomicAdd(&out[(size_t)t * D_ + col], scale * acc[i][j][r]);
                }
            }
        }
}

// ---------------------------------------------------------------------------
// RoPE cos/sin tables (np f32 semantics via f64 pow/cos/sin)
// ---------------------------------------------------------------------------
__global__ __launch_bounds__(256) void rope_table_kernel(
    float* __restrict__ ctab, float* __restrict__ stab)
{
    const int i = blockIdx.x * 256 + threadIdx.x;   // S_*32
    if (i >= S_ * 32) return;
    const int s = i >> 5, p = i & 31;
    const double e = (double)(2 * p) / 64.0;
    const float pf = (float)pow(10000.0, e);
    const float invf = 1.0f / pf;
    const float fr = (float)s * invf;
    ctab[i] = (float)cos((double)fr);
    stab[i] = (float)sin((double)fr);
}

// ---------------------------------------------------------------------------
// Fused flash attention — two-word bf16 MFMA, online softmax, single pass.
// Inputs are PRE-SPLIT hi/lo bf16 planes (qk: [T][2048] rotated q|k;
// vT: [bh][64][512]) so the loop does pure 16B vector staging.
// Grid (bh=64, qt=16), 256 thr = 4 waves; wave w owns kv/d chunk w*16..+15.
// ---------------------------------------------------------------------------
__global__ __launch_bounds__(256, 4) void attn_fused_kernel(
    const ushort_t* __restrict__ qkh, const ushort_t* __restrict__ qkl,
    const ushort_t* __restrict__ vTh, const ushort_t* __restrict__ vTl,
    ushort_t* __restrict__ aoh, ushort_t* __restrict__ aol)
{
    const int bh = blockIdx.x;                 // b*16+h
    const int qt = blockIdx.y;
    const int b = bh >> 4, h = bh & 15;
    const int q0 = qt * 32;
    const int nchunk = (qt >> 1) + 1;

    // bf16 hi/lo tiles, row stride 72 (pad 8) keeps b128 reads 16B-aligned
    __shared__ __align__(16) ushort_t qsh[32 * 72], qsl[32 * 72];  // Q rows (q, d)
    __shared__ __align__(16) ushort_t kvh[64 * 72], kvl[64 * 72];  // K rows, then V^T rows
    __shared__ __align__(16) ushort_t psh[32 * 72], psl[32 * 72];  // P rows (q, kv)
    __shared__ __align__(16) float redm[32][4];      // per-wave row max
    __shared__ __align__(16) float redl[32][4];      // per-wave row sum

    const int tid = threadIdx.x, w = tid >> 6, lane = tid & 63;
    const int lm = lane & 15, lq = lane >> 4;
    const size_t vbase = (size_t)bh * (HD_ * S_);

    // ---- stage Q once: pure 16B copies from planes
    {
        const int row = tid >> 3, g = tid & 7;
        const size_t src = (size_t)(b * S_ + q0 + row) * 2048 + h * HD_ + g * 8;
        *(uint4*)(qsh + row * 72 + g * 8) = *(const uint4*)(qkh + src);
        *(uint4*)(qsl + row * 72 + g * 8) = *(const uint4*)(qkl + src);
    }

    // running state: rows q = i*16 + lq*4 + r, col d = w*16 + lm
    float mrun[2][4], lrun[2][4];
    floatx4 oacc[2] = {};
#pragma unroll
    for (int i = 0; i < 2; i++)
#pragma unroll
        for (int r = 0; r < 4; r++) { mrun[i][r] = -INFINITY; lrun[i][r] = 0.f; }

    for (int c = 0; c < nchunk; c++) {
        const int c0 = c * 64;

        // ---- stage K chunk: 16B copies from planes into shared K/V buffer
#pragma unroll
        for (int it = 0; it < 2; it++) {
            const int i = tid + it * 256;
            const int row = i >> 3, g = i & 7;
            const size_t src = (size_t)(b * S_ + c0 + row) * 2048 + 1024 + h * HD_ + g * 8;
            *(uint4*)(kvh + row * 72 + g * 8) = *(const uint4*)(qkh + src);
            *(uint4*)(kvl + row * 72 + g * 8) = *(const uint4*)(qkl + src);
        }
        // ---- prefetch V^T rows into registers; latency hides under QK
        uint4 vrh[2], vrl[2];
#pragma unroll
        for (int it = 0; it < 2; it++) {
            const int i = tid + it * 256;
            const int row = i >> 3, g = i & 7;     // row = d (0..63)
            const size_t src = vbase + (size_t)row * S_ + c0 + g * 8;
            vrh[it] = *(const uint4*)(vTh + src);
            vrl[it] = *(const uint4*)(vTl + src);
        }
        __syncthreads();   // K (and Q on first iter) visible

        // ---- scores: wave w -> S[32 q][16 kv] chunk; 3 MFMAs per product
        floatx4 acc[2] = {};
#pragma unroll
        for (int k0 = 0; k0 < 64; k0 += 32) {
            const bf16x8 bh16 = *(const bf16x8*)(kvh + (w * 16 + lm) * 72 + k0 + lq * 8);
            const bf16x8 bl16 = *(const bf16x8*)(kvl + (w * 16 + lm) * 72 + k0 + lq * 8);
#pragma unroll
            for (int i = 0; i < 2; i++) {
                const bf16x8 ah = *(const bf16x8*)(qsh + (i * 16 + lm) * 72 + k0 + lq * 8);
                const bf16x8 al = *(const bf16x8*)(qsl + (i * 16 + lm) * 72 + k0 + lq * 8);
                acc[i] = __builtin_amdgcn_mfma_f32_16x16x32_bf16(ah, bh16, acc[i], 0, 0, 0);
                acc[i] = __builtin_amdgcn_mfma_f32_16x16x32_bf16(al, bh16, acc[i], 0, 0, 0);
                acc[i] = __builtin_amdgcn_mfma_f32_16x16x32_bf16(ah, bl16, acc[i], 0, 0, 0);
            }
        }

        // ---- mask + scale, per-row max over this wave's 16 kv
        float sv[2][4];
        const int kvg = c0 + w * 16 + lm;
#pragma unroll
        for (int i = 0; i < 2; i++)
#pragma unroll
            for (int r = 0; r < 4; r++) {
                const int qg = q0 + i * 16 + lq * 4 + r;
                float v = (kvg <= qg) ? acc[i][r] * 0.125f : -INFINITY;
                sv[i][r] = v;
#pragma unroll
                for (int off = 1; off < 16; off <<= 1) v = fmaxf(v, __shfl_xor(v, off));
                if (lm == 0) redm[i * 16 + lq * 4 + r][w] = v;
            }
        __syncthreads();   // redm complete; all K reads done

        // ---- stage V^T from registers (overwrites K) — vector stores
#pragma unroll
        for (int it = 0; it < 2; it++) {
            const int i = tid + it * 256;
            const int row = i >> 3, g = i & 7;
            *(uint4*)(kvh + row * 72 + g * 8) = vrh[it];
            *(uint4*)(kvl + row * 72 + g * 8) = vrl[it];
        }

        // ---- online softmax: new row max, p = exp(s - m'), rescale factor
        float sclr[2][4];
#pragma unroll
        for (int i = 0; i < 2; i++)
#pragma unroll
            for (int r = 0; r < 4; r++) {
                const int q = i * 16 + lq * 4 + r;
                const float4 m4 = *(const float4*)&redm[q][0];
                const float Mc = fmaxf(fmaxf(m4.x, m4.y), fmaxf(m4.z, m4.w));
                const float Mn = fmaxf(mrun[i][r], Mc);
                const float p = expf(sv[i][r] - Mn);
                ushort_t ph, pl;
                split2(p, ph, pl);
                psh[q * 72 + w * 16 + lm] = ph;
                psl[q * 72 + w * 16 + lm] = pl;
                float sum = p;
#pragma unroll
                for (int off = 1; off < 16; off <<= 1) sum += __shfl_xor(sum, off);
                if (lm == 0) redl[q][w] = sum;
                sclr[i][r] = expf(mrun[i][r] - Mn);   // 0 on first chunk
                mrun[i][r] = Mn;
            }
        __syncthreads();   // ps, V^T, redl ready

        // ---- update l, rescale O
#pragma unroll
        for (int i = 0; i < 2; i++)
#pragma unroll
            for (int r = 0; r < 4; r++) {
                const int q = i * 16 + lq * 4 + r;
                const float4 l4 = *(const float4*)&redl[q][0];
                const float lc = l4.x + l4.y + l4.z + l4.w;
                lrun[i][r] = lrun[i][r] * sclr[i][r] + lc;
                oacc[i][r] *= sclr[i][r];
            }

        // ---- PV: O[32 q][16 d chunk w] += (Ph+Pl) · (Vh+Vl)^T
#pragma unroll
        for (int k0 = 0; k0 < 64; k0 += 32) {
            const bf16x8 bh16 = *(const bf16x8*)(kvh + (w * 16 + lm) * 72 + k0 + lq * 8);
            const bf16x8 bl16 = *(const bf16x8*)(kvl + (w * 16 + lm) * 72 + k0 + lq * 8);
#pragma unroll
            for (int i = 0; i < 2; i++) {
                const bf16x8 ah = *(const bf16x8*)(psh + (i * 16 + lm) * 72 + k0 + lq * 8);
                const bf16x8 al = *(const bf16x8*)(psl + (i * 16 + lm) * 72 + k0 + lq * 8);
                oacc[i] = __builtin_amdgcn_mfma_f32_16x16x32_bf16(ah, bh16, oacc[i], 0, 0, 0);
                oacc[i] = __builtin_amdgcn_mfma_f32_16x16x32_bf16(al, bh16, oacc[i], 0, 0, 0);
                oacc[i] = __builtin_amdgcn_mfma_f32_16x16x32_bf16(ah, bl16, oacc[i], 0, 0, 0);
            }
        }
        __syncthreads();   // PV reads done before next chunk overwrites kv/ps
    }

    // ---- epilogue: normalize and emit hi/lo bf16 planes
    const int col = h * HD_ + w * 16 + lm;
#pragma unroll
    for (int i = 0; i < 2; i++)
#pragma unroll
        for (int r = 0; r < 4; r++) {
            const int q = i * 16 + lq * 4 + r;
            const int t = b * S_ + q0 + q;
            const float v = oacc[i][r] / lrun[i][r];
            ushort_t hh, ll;
            split2(v, hh, ll);
            aoh[(size_t)t * D_ + col] = hh;
            aol[(size_t)t * D_ + col] = ll;
        }
}

__global__ void zero_route_kernel(int* __restrict__ cnt)
{
    if (threadIdx.x < 8) cnt[threadIdx.x] = 0;
}

// ---------------------------------------------------------------------------
// dist = probs.mean(0); lb = E * sum(dist^2); writes out tail.
// ---------------------------------------------------------------------------
__global__ __launch_bounds__(256) void reduce_dist_kernel(
    const float* __restrict__ probs, float* __restrict__ out)
{
    __shared__ float part[256];
    __shared__ float dist8[8];
    const int tid = threadIdx.x;
    const int e = tid & 7, chunk = tid >> 3;   // 32 chunks
    float s = 0.f;
    for (int t = chunk; t < T_; t += 32) s += probs[t * 8 + e];
    part[tid] = s;
    __syncthreads();
    if (tid < 8) {
        float tot = 0.f;
        for (int c = 0; c < 32; c++) tot += part[c * 8 + tid];
        const float dv = tot * (1.0f / T_);
        dist8[tid] = dv;
        out[(size_t)T_ * D_ + 1 + tid] = dv;
    }
    __syncthreads();
    if (tid == 0) {
        float s2 = 0.f;
        for (int k = 0; k < 8; k++) s2 += dist8[k] * dist8[k];
        out[(size_t)T_ * D_] = (float)E_ * s2;
    }
}

// ---------------------------------------------------------------------------
// Launch
// ---------------------------------------------------------------------------
extern "C" void kernel_launch(void* const* d_in, const int* in_sizes, int n_in,
                              void* d_out, int out_size, void* d_ws, size_t ws_size,
                              hipStream_t stream)
{
    const float* x      = (const float*)d_in[0];
    const float* ln1_g  = (const float*)d_in[1];
    const float* ln1_b  = (const float*)d_in[2];
    const float* ln2_g  = (const float*)d_in[3];
    const float* ln2_b  = (const float*)d_in[4];
    const float* w_qkv  = (const float*)d_in[5];
    const float* w_o    = (const float*)d_in[6];
    const float* gate_w = (const float*)d_in[7];
    const float* w_gate = (const float*)d_in[8];
    const float* w_up   = (const float*)d_in[9];
    const float* w_down = (const float*)d_in[10];
    float* out = (float*)d_out;

    char* ws = (char*)d_ws;
    size_t off = 0;
    auto alloc = [&](size_t bytes) { size_t o = off; off += (bytes + 255) & ~(size_t)255; return o; };
    // persistent-through-MoE region
    ushort_t* wguT  = (ushort_t*)(ws + alloc((size_t)E_ * GU_ * D_ * 2));   // 58.7 MB
    ushort_t* wdT   = (ushort_t*)(ws + alloc((size_t)E_ * D_ * HID_ * 2));  // 29.4 MB
    ushort_t* xnh   = (ushort_t*)(ws + alloc((size_t)T_ * D_ * 4));         // hi+lo planes
    ushort_t* xnl   = xnh + (size_t)T_ * D_;
    ushort_t* xn2   = (ushort_t*)(ws + alloc((size_t)T_ * D_ * 2));
    int*      cnt   = (int*)     (ws + alloc(64));
    int*      tok   = (int*)     (ws + alloc((size_t)E_ * T_ * 4));
    float*    wt    = (float*)   (ws + alloc((size_t)E_ * T_ * 4));
    float*    probs = (float*)   (ws + alloc((size_t)T_ * E_ * 4));
    float*    ctab  = (float*)   (ws + alloc((size_t)S_ * 32 * 4));
    float*    stab  = (float*)   (ws + alloc((size_t)S_ * 32 * 4));
    // scratch union (59 MB, aliased by lifetime):
    //   A (QKV GEMM):  wqkvT hi/lo [0,12.58M) read; qkh/qkl [12.58M,29.36M)
    //                  + vT hi/lo [29.36M,37.75M) written by fused epilogue
    //   B (attn):      qkh/qkl/vT read; aoh/aol [37.75M,46.14M) written
    //   C (W_O):       x1 [0,8.39M) + woT [8.39M,12.58M) (wqkvT dead);
    //                  aoh/aol read
    //   D (MoE):       Hc [0,58.7M) (everything else dead)
    const size_t scratch0 = alloc((size_t)59 << 20);
    char* sc = ws + scratch0;
    ushort_t* wqkvTh= (ushort_t*)(sc);
    ushort_t* wqkvTl= wqkvTh + (size_t)D3_ * D_;                  // ends 12,582,912
    ushort_t* qkh   = (ushort_t*)(sc + 12582912);
    ushort_t* qkl   = qkh + (size_t)T_ * 2048;                    // ends 29,360,128
    ushort_t* vTh   = (ushort_t*)(sc + 29360128);
    ushort_t* vTl   = vTh + (size_t)64 * HD_ * S_;                // ends 37,748,736
    ushort_t* aoh   = (ushort_t*)(sc + 37748736);
    ushort_t* aol   = aoh + (size_t)T_ * D_;                      // ends 46,137,344
    float*    x1    = (float*)   (sc);                            // W_O phase
    ushort_t* woTh  = (ushort_t*)(sc + 8388608);
    ushort_t* woTl  = woTh + (size_t)D_ * D_;
    ushort_t* Hc    = (ushort_t*)(sc);                            // MoE phase
    (void)ws_size; (void)in_sizes; (void)n_in; (void)out_size;

    // weight transposes -> bf16 (N x K); gate/up interleaved into wguT
    hipLaunchKernelGGL(transpose_bf16_kernel, dim3(HID_ / 64, D_ / 64, E_), dim3(256), 0, stream,
                       w_gate, wguT, D_, HID_, 2, 0, (long)GU_ * D_);
    hipLaunchKernelGGL(transpose_bf16_kernel, dim3(HID_ / 64, D_ / 64, E_), dim3(256), 0, stream,
                       w_up, wguT, D_, HID_, 2, 1, (long)GU_ * D_);
    hipLaunchKernelGGL(transpose_bf16_kernel, dim3(D_ / 64, HID_ / 64, E_), dim3(256), 0, stream,
                       w_down, wdT, HID_, D_, 1, 0, (long)D_ * HID_);

    // w_qkv (D x 3D) -> hi/lo bf16 planes (3D x D)
    hipLaunchKernelGGL(transpose_split_kernel, dim3(D3_ / 64, D_ / 64), dim3(256), 0, stream,
                       w_qkv, wqkvTh, wqkvTl, D_, D3_);

    // RoPE tables
    hipLaunchKernelGGL(rope_table_kernel, dim3((S_ * 32 + 255) / 256), dim3(256), 0, stream,
                       ctab, stab);

    // LN1 -> hi/lo bf16 planes (no gating)
    hipLaunchKernelGGL(ln_kernel, dim3(T_), dim3(256), 0, stream,
                       x, ln1_g, ln1_b, (ushort_t*)nullptr, xnh, xnl,
                       (const float*)nullptr, (int*)nullptr, (int*)nullptr,
                       (float*)nullptr, (float*)nullptr);

    // QKV GEMM with fused RoPE+split+V-transpose epilogue: grid (24,16)
    hipLaunchKernelGGL(qkv_rope_gemm_kernel, dim3(D3_ / 128, T_ / 128), dim3(256), 0, stream,
                       xnh, xnl, wqkvTh, wqkvTl, ctab, stab, qkh, qkl, vTh, vTl);

    // fused flash attention -> attn output hi/lo planes
    hipLaunchKernelGGL(attn_fused_kernel, dim3(64, 16), dim3(256), 0, stream,
                       qkh, qkl, vTh, vTl, aoh, aol);

    // w_o (D x D) -> hi/lo bf16 planes (wqkvT dead now)
    hipLaunchKernelGGL(transpose_split_kernel, dim3(D_ / 64, D_ / 64), dim3(256), 0, stream,
                       w_o, woTh, woTl, D_, D_);

    // W_O two-word bf16 MFMA GEMM + residual -> x1 AND out
    hipLaunchKernelGGL(gemm2w_kernel, dim3(D_ / 128, T_ / 128), dim3(256), 0, stream,
                       aoh, aol, woTh, woTl, x, x1, out, D_);

    // routing counters must be zero before LN2's fused gating
    hipLaunchKernelGGL(zero_route_kernel, dim3(1), dim3(64), 0, stream, cnt);

    // LN2 (bf16) with FUSED gating + routing (bitwise-identical gate loop)
    hipLaunchKernelGGL(ln_kernel, dim3(T_), dim3(256), 0, stream,
                       x1, ln2_g, ln2_b, xn2, (ushort_t*)nullptr, (ushort_t*)nullptr,
                       gate_w, cnt, tok, wt, probs);

    // aux outputs
    hipLaunchKernelGGL(reduce_dist_kernel, dim3(1), dim3(256), 0, stream, probs, out);

    // MoE routed: fused gate+up (+silu), then weighted down (split-K=2)
    hipLaunchKernelGGL(gateup_idx_kernel, dim3(GU_ / 128, T_ / 128, E_), dim3(256), 0, stream,
                       xn2, wguT, cnt, tok, Hc);
    hipLaunchKernelGGL(down_idx_kernel, dim3(D_ / 128, T_ / 128, E_ * 2), dim3(256), 0, stream,
                       Hc, wdT, cnt, tok, wt, out);
}

// Round 10
// 593.647 us; speedup vs baseline: 1.0625x; 1.0478x over previous
//
#include <hip/hip_runtime.h>
#include <hip/hip_bf16.h>
#include <math.h>

// ---------------------------------------------------------------------------
// Shapes (fixed by the problem)
// ---------------------------------------------------------------------------
#define B_    4
#define S_    512
#define D_    1024
#define T_    2048          // B*S tokens
#define H_    16
#define HD_   64
#define E_    8
#define HID_  1792
#define D3_   3072
#define GU_   (2 * HID_)    // 3584 interleaved gate/up columns

typedef unsigned short ushort_t;
typedef __bf16 bf16x8 __attribute__((ext_vector_type(8)));
typedef float  floatx4 __attribute__((ext_vector_type(4)));

__device__ inline float bf2f(ushort_t u) {
    return __uint_as_float(((unsigned)u) << 16);
}
__device__ inline ushort_t f2bf(float f) {
    __hip_bfloat16 h = __float2bfloat16(f);
    return __builtin_bit_cast(ushort_t, h);
}

// two-word bf16 split: x ~= hi + lo with combined rel error ~2^-17.
// hi = truncated-bf16(x) (exact prefix), lo = rne-bf16(x - hi).
__device__ __forceinline__ void split2(float x, ushort_t& h, ushort_t& l) {
    const unsigned ub = __float_as_uint(x);
    h = (ushort_t)(ub >> 16);
    l = f2bf(x - __uint_as_float(ub & 0xFFFF0000u));
}

// async 16B/lane global->LDS; lds dest wave-uniform base (+lane*16 by HW)
__device__ __forceinline__ void gl2lds16(const ushort_t* g, ushort_t* l) {
    __builtin_amdgcn_global_load_lds(
        (const __attribute__((address_space(1))) void*)g,
        (__attribute__((address_space(3))) void*)l, 16, 0, 0);
}

// ---------------------------------------------------------------------------
// Vectorized transpose + fp32->bf16: in (z,R,C) f32 ->
// out[z*outEstride + (c*mul+add)*R + r]. 64x64 tiles, float4 loads (16B/lane),
// packed 8-ushort stores (16B/lane, contiguous along r). Bit-identical values.
// ---------------------------------------------------------------------------
__global__ __launch_bounds__(256) void transpose_bf16_kernel(
    const float* __restrict__ in, ushort_t* __restrict__ out,
    int R, int C, int mul, int add, long outEstride)
{
    __shared__ float tile[64][65];
    const int bx = blockIdx.x * 64;           // c
    const int by = blockIdx.y * 64;           // r
    const size_t iofs = (size_t)blockIdx.z * R * C;
    const size_t oofs = (size_t)blockIdx.z * outEstride;
    const int tid = threadIdx.x;
    const int lr = tid >> 4;                  // 0..15
    const int lc4 = (tid & 15) * 4;           // 0..60
#pragma unroll
    for (int i = 0; i < 4; i++) {
        const int r = lr + i * 16;
        const float4 v = *(const float4*)(in + iofs + (size_t)(by + r) * C + bx + lc4);
        tile[r][lc4 + 0] = v.x;
        tile[r][lc4 + 1] = v.y;
        tile[r][lc4 + 2] = v.z;
        tile[r][lc4 + 3] = v.w;
    }
    __syncthreads();
    const int sc = tid >> 3;                  // 0..31
    const int rg = (tid & 7) * 8;             // 0..56
#pragma unroll
    for (int i = 0; i < 2; i++) {
        const int c = sc + i * 32;
        ushort4 o0, o1;
        o0.x = f2bf(tile[rg + 0][c]); o0.y = f2bf(tile[rg + 1][c]);
        o0.z = f2bf(tile[rg + 2][c]); o0.w = f2bf(tile[rg + 3][c]);
        o1.x = f2bf(tile[rg + 4][c]); o1.y = f2bf(tile[rg + 5][c]);
        o1.z = f2bf(tile[rg + 6][c]); o1.w = f2bf(tile[rg + 7][c]);
        ushort_t* op = out + oofs + (size_t)((bx + c) * mul + add) * R + by + rg;
        *(ushort4*)(op)     = o0;
        *(ushort4*)(op + 4) = o1;
    }
}

// ---------------------------------------------------------------------------
// Vectorized transpose + fp32 -> two-word bf16 planes (same access pattern).
// ---------------------------------------------------------------------------
__global__ __launch_bounds__(256) void transpose_split_kernel(
    const float* __restrict__ in, ushort_t* __restrict__ outh,
    ushort_t* __restrict__ outl, int R, int C)
{
    __shared__ float tile[64][65];
    const int bx = blockIdx.x * 64;           // c
    const int by = blockIdx.y * 64;           // r
    const int tid = threadIdx.x;
    const int lr = tid >> 4;
    const int lc4 = (tid & 15) * 4;
#pragma unroll
    for (int i = 0; i < 4; i++) {
        const int r = lr + i * 16;
        const float4 v = *(const float4*)(in + (size_t)(by + r) * C + bx + lc4);
        tile[r][lc4 + 0] = v.x;
        tile[r][lc4 + 1] = v.y;
        tile[r][lc4 + 2] = v.z;
        tile[r][lc4 + 3] = v.w;
    }
    __syncthreads();
    const int sc = tid >> 3;
    const int rg = (tid & 7) * 8;
#pragma unroll
    for (int i = 0; i < 2; i++) {
        const int c = sc + i * 32;
        ushort4 h0, l0, h1, l1;
        split2(tile[rg + 0][c], h0.x, l0.x); split2(tile[rg + 1][c], h0.y, l0.y);
        split2(tile[rg + 2][c], h0.z, l0.z); split2(tile[rg + 3][c], h0.w, l0.w);
        split2(tile[rg + 4][c], h1.x, l1.x); split2(tile[rg + 5][c], h1.y, l1.y);
        split2(tile[rg + 6][c], h1.z, l1.z); split2(tile[rg + 7][c], h1.w, l1.w);
        const size_t ob = (size_t)(bx + c) * R + by + rg;
        *(ushort4*)(outh + ob)     = h0;
        *(ushort4*)(outh + ob + 4) = h1;
        *(ushort4*)(outl + ob)     = l0;
        *(ushort4*)(outl + ob + 4) = l1;
    }
}

// ---------------------------------------------------------------------------
// LayerNorm: x (rows x 1024) f32 -> optional bf16 out and/or hi/lo planes.
// Optional FUSED GATING (gate_w != null): wave 0 replays the exact
// gate_kernel loop (same per-lane d-stride, fmaf order, shfl tree, bf16
// rounding) reading the bf16 row from LDS -> bitwise-identical logits.
// ---------------------------------------------------------------------------
__global__ __launch_bounds__(256) void ln_kernel(
    const float* __restrict__ x, const float* __restrict__ g,
    const float* __restrict__ b, ushort_t* __restrict__ outb,
    ushort_t* __restrict__ outh, ushort_t* __restrict__ outl,
    const float* __restrict__ gate_w, int* __restrict__ cnt,
    int* __restrict__ tok, float* __restrict__ wt,
    float* __restrict__ probs)
{
    const int t = blockIdx.x;
    const int tid = threadIdx.x;
    const int wave = tid >> 6, lane = tid & 63;
    const float4 v = ((const float4*)(x + (size_t)t * D_))[tid];

    float s = v.x + v.y + v.z + v.w;
#pragma unroll
    for (int off = 32; off; off >>= 1) s += __shfl_xor(s, off);
    __shared__ float red1[4];
    __shared__ float red2[4];
    __shared__ ushort_t xb[1024];
    if (lane == 0) red1[wave] = s;
    __syncthreads();
    const float mu = (red1[0] + red1[1] + red1[2] + red1[3]) * (1.0f / D_);

    const float dx = v.x - mu, dy = v.y - mu, dz = v.z - mu, dw = v.w - mu;
    float vs = dx * dx + dy * dy + dz * dz + dw * dw;
#pragma unroll
    for (int off = 32; off; off >>= 1) vs += __shfl_xor(vs, off);
    if (lane == 0) red2[wave] = vs;
    __syncthreads();
    const float var = (red2[0] + red2[1] + red2[2] + red2[3]) * (1.0f / D_);
    const float rs = 1.0f / sqrtf(var + 1e-5f);

    const float4 gg = ((const float4*)g)[tid];
    const float4 bb = ((const float4*)b)[tid];
    float4 o;
    o.x = dx * rs * gg.x + bb.x;
    o.y = dy * rs * gg.y + bb.y;
    o.z = dz * rs * gg.z + bb.z;
    o.w = dw * rs * gg.w + bb.w;
    ushort4 ob;
    ob.x = f2bf(o.x); ob.y = f2bf(o.y); ob.z = f2bf(o.z); ob.w = f2bf(o.w);
    if (outb) ((ushort4*)(outb + (size_t)t * D_))[tid] = ob;
    if (outh) {
        ushort4 oh, ol;
        split2(o.x, oh.x, ol.x); split2(o.y, oh.y, ol.y);
        split2(o.z, oh.z, ol.z); split2(o.w, oh.w, ol.w);
        ((ushort4*)(outh + (size_t)t * D_))[tid] = oh;
        ((ushort4*)(outl + (size_t)t * D_))[tid] = ol;
    }

    if (gate_w) {
        *(ushort4*)(xb + tid * 4) = ob;
        __syncthreads();
        if (tid < 64) {
            float acc[8] = {0, 0, 0, 0, 0, 0, 0, 0};
            for (int d = tid; d < D_; d += 64) {
                const float xv = bf2f(xb[d]);
                const float4 g0 = ((const float4*)(gate_w + d * 8))[0];
                const float4 g1 = ((const float4*)(gate_w + d * 8))[1];
                acc[0] = fmaf(xv, bf2f(f2bf(g0.x)), acc[0]);
                acc[1] = fmaf(xv, bf2f(f2bf(g0.y)), acc[1]);
                acc[2] = fmaf(xv, bf2f(f2bf(g0.z)), acc[2]);
                acc[3] = fmaf(xv, bf2f(f2bf(g0.w)), acc[3]);
                acc[4] = fmaf(xv, bf2f(f2bf(g1.x)), acc[4]);
                acc[5] = fmaf(xv, bf2f(f2bf(g1.y)), acc[5]);
                acc[6] = fmaf(xv, bf2f(f2bf(g1.z)), acc[6]);
                acc[7] = fmaf(xv, bf2f(f2bf(g1.w)), acc[7]);
            }
#pragma unroll
            for (int e = 0; e < 8; e++) {
#pragma unroll
                for (int off = 32; off; off >>= 1) acc[e] += __shfl_xor(acc[e], off);
                acc[e] = bf2f(f2bf(acc[e]));   // bf16 result of the bf16 matmul
            }
            if (tid == 0) {
                int i1 = 0;
                for (int e = 1; e < 8; e++) if (acc[e] > acc[i1]) i1 = e;
                int i2 = (i1 == 0) ? 1 : 0;
                for (int e = 0; e < 8; e++) if (e != i1 && acc[e] > acc[i2]) i2 = e;
                const float e2 = expf(acc[i2] - acc[i1]);
                const float w1 = 1.f / (1.f + e2);
                const float w2 = e2 * w1;
                const int p1 = atomicAdd(&cnt[i1], 1);
                tok[i1 * T_ + p1] = t; wt[i1 * T_ + p1] = w1;
                const int p2 = atomicAdd(&cnt[i2], 1);
                tok[i2 * T_ + p2] = t; wt[i2 * T_ + p2] = w2;
                const float mx = acc[i1];
                float se = 0.f, pe[8];
                for (int e = 0; e < 8; e++) { pe[e] = expf(acc[e] - mx); se += pe[e]; }
                const float inv = 1.f / se;
                for (int e = 0; e < 8; e++) probs[t * 8 + e] = pe[e] * inv;
            }
        }
    }
}

// ---------------------------------------------------------------------------
// Two-word bf16 MFMA GEMM, 128x64 tile (balanced grids): C[M x ncols] =
// (Ah+Al)[M x 1024] · (Bh+Bl)[N x 1024]^T (+ optional residual / 2nd out).
// 4 waves x (32 rows x 64 cols), BK=32, 3 MFMAs per product (hh + lh + hl).
// Per-element accumulation order identical to the 128x128 variant ->
// bit-identical results.
// ---------------------------------------------------------------------------
__global__ __launch_bounds__(256) void gemm2w_n64_kernel(
    const ushort_t* __restrict__ Ah, const ushort_t* __restrict__ Al,
    const ushort_t* __restrict__ Bh, const ushort_t* __restrict__ Bl,
    const float* __restrict__ res, float* __restrict__ C,
    float* __restrict__ C2, int ncols)
{
    const int row0 = blockIdx.y * 128, col0 = blockIdx.x * 64;

    __shared__ __align__(16) ushort_t Ash[128 * 32], Asl[128 * 32];
    __shared__ __align__(16) ushort_t Bsh[64 * 32],  Bsl[64 * 32];
    const int tid = threadIdx.x, w = tid >> 6, lane = tid & 63;
    const int lr = lane >> 2, lc = (lane & 3) * 8;
    const int wm = w * 32;
    const int lm = lane & 15, lq = lane >> 4;

    floatx4 acc[2][4] = {};

    const ushort_t* Aph = Ah + (size_t)(row0 + w * 16 + lr) * D_ + lc;
    const ushort_t* Apl = Al + (size_t)(row0 + w * 16 + lr) * D_ + lc;
    const ushort_t* Bph = Bh + (size_t)(col0 + w * 16 + lr) * D_ + lc;
    const ushort_t* Bpl = Bl + (size_t)(col0 + w * 16 + lr) * D_ + lc;

    for (int k0 = 0; k0 < D_; k0 += 32) {
        __syncthreads();
        gl2lds16(Aph + k0, Ash + w * 512);
        gl2lds16(Aph + k0 + (size_t)64 * D_, Ash + 2048 + w * 512);
        gl2lds16(Apl + k0, Asl + w * 512);
        gl2lds16(Apl + k0 + (size_t)64 * D_, Asl + 2048 + w * 512);
        gl2lds16(Bph + k0, Bsh + w * 512);
        gl2lds16(Bpl + k0, Bsl + w * 512);
        __syncthreads();
        bf16x8 ah[2], al[2], bh16[4], bl16[4];
#pragma unroll
        for (int i = 0; i < 2; i++) {
            ah[i] = *(const bf16x8*)(Ash + (wm + i * 16 + lm) * 32 + lq * 8);
            al[i] = *(const bf16x8*)(Asl + (wm + i * 16 + lm) * 32 + lq * 8);
        }
#pragma unroll
        for (int j = 0; j < 4; j++) {
            bh16[j] = *(const bf16x8*)(Bsh + (j * 16 + lm) * 32 + lq * 8);
            bl16[j] = *(const bf16x8*)(Bsl + (j * 16 + lm) * 32 + lq * 8);
        }
#pragma unroll
        for (int i = 0; i < 2; i++)
#pragma unroll
            for (int j = 0; j < 4; j++) {
                acc[i][j] = __builtin_amdgcn_mfma_f32_16x16x32_bf16(ah[i], bh16[j], acc[i][j], 0, 0, 0);
                acc[i][j] = __builtin_amdgcn_mfma_f32_16x16x32_bf16(al[i], bh16[j], acc[i][j], 0, 0, 0);
                acc[i][j] = __builtin_amdgcn_mfma_f32_16x16x32_bf16(ah[i], bl16[j], acc[i][j], 0, 0, 0);
            }
    }

#pragma unroll
    for (int i = 0; i < 2; i++)
#pragma unroll
        for (int r = 0; r < 4; r++) {
            const int row = row0 + wm + i * 16 + lq * 4 + r;
#pragma unroll
            for (int j = 0; j < 4; j++) {
                const int col = col0 + j * 16 + lm;
                const size_t idx = (size_t)row * ncols + col;
                float o = acc[i][j][r];
                if (res) o += res[idx];
                C[idx] = o;
                if (C2) C2[idx] = o;
            }
        }
}

// ---------------------------------------------------------------------------
// QKV GEMM (128x64 tile) with fused RoPE + two-word split + V-transpose
// epilogue. Grid (48,16) = 768 blocks = 3.0/CU (balanced).
// col < 2048 (q,k): rotation partner is adjacent col = adjacent lane
// (__shfl_xor(v,1)); col >= 2048 (V): scatter into vT[bh][d][s] planes.
// ---------------------------------------------------------------------------
__global__ __launch_bounds__(256) void qkv_rope_gemm_kernel(
    const ushort_t* __restrict__ Ah, const ushort_t* __restrict__ Al,
    const ushort_t* __restrict__ Bh, const ushort_t* __restrict__ Bl,
    const float* __restrict__ ctab, const float* __restrict__ stab,
    ushort_t* __restrict__ qkh, ushort_t* __restrict__ qkl,
    ushort_t* __restrict__ vTh, ushort_t* __restrict__ vTl)
{
    const int row0 = blockIdx.y * 128, col0 = blockIdx.x * 64;

    __shared__ __align__(16) ushort_t Ash[128 * 32], Asl[128 * 32];
    __shared__ __align__(16) ushort_t Bsh[64 * 32],  Bsl[64 * 32];
    const int tid = threadIdx.x, w = tid >> 6, lane = tid & 63;
    const int lr = lane >> 2, lc = (lane & 3) * 8;
    const int wm = w * 32;
    const int lm = lane & 15, lq = lane >> 4;

    floatx4 acc[2][4] = {};

    const ushort_t* Aph = Ah + (size_t)(row0 + w * 16 + lr) * D_ + lc;
    const ushort_t* Apl = Al + (size_t)(row0 + w * 16 + lr) * D_ + lc;
    const ushort_t* Bph = Bh + (size_t)(col0 + w * 16 + lr) * D_ + lc;
    const ushort_t* Bpl = Bl + (size_t)(col0 + w * 16 + lr) * D_ + lc;

    for (int k0 = 0; k0 < D_; k0 += 32) {
        __syncthreads();
        gl2lds16(Aph + k0, Ash + w * 512);
        gl2lds16(Aph + k0 + (size_t)64 * D_, Ash + 2048 + w * 512);
        gl2lds16(Apl + k0, Asl + w * 512);
        gl2lds16(Apl + k0 + (size_t)64 * D_, Asl + 2048 + w * 512);
        gl2lds16(Bph + k0, Bsh + w * 512);
        gl2lds16(Bpl + k0, Bsl + w * 512);
        __syncthreads();
        bf16x8 ah[2], al[2], bh16[4], bl16[4];
#pragma unroll
        for (int i = 0; i < 2; i++) {
            ah[i] = *(const bf16x8*)(Ash + (wm + i * 16 + lm) * 32 + lq * 8);
            al[i] = *(const bf16x8*)(Asl + (wm + i * 16 + lm) * 32 + lq * 8);
        }
#pragma unroll
        for (int j = 0; j < 4; j++) {
            bh16[j] = *(const bf16x8*)(Bsh + (j * 16 + lm) * 32 + lq * 8);
            bl16[j] = *(const bf16x8*)(Bsl + (j * 16 + lm) * 32 + lq * 8);
        }
#pragma unroll
        for (int i = 0; i < 2; i++)
#pragma unroll
            for (int j = 0; j < 4; j++) {
                acc[i][j] = __builtin_amdgcn_mfma_f32_16x16x32_bf16(ah[i], bh16[j], acc[i][j], 0, 0, 0);
                acc[i][j] = __builtin_amdgcn_mfma_f32_16x16x32_bf16(al[i], bh16[j], acc[i][j], 0, 0, 0);
                acc[i][j] = __builtin_amdgcn_mfma_f32_16x16x32_bf16(ah[i], bl16[j], acc[i][j], 0, 0, 0);
            }
    }

    const bool isV = (col0 >= 2 * D_);   // block-uniform (64-col tiles, V at 2048)
#pragma unroll
    for (int i = 0; i < 2; i++)
#pragma unroll
        for (int j = 0; j < 4; j++) {
            const int col = col0 + j * 16 + lm;
#pragma unroll
            for (int r = 0; r < 4; r++) {
                const int row = row0 + wm + i * 16 + lq * 4 + r;   // token t
                float v = acc[i][j][r];
                if (!isV) {
                    // RoPE: partner col = col^1 lives in lane^1 (same i,j,r)
                    const float vp = __shfl_xor(v, 1);
                    const int pair = (col & 63) >> 1;
                    const int s = row & (S_ - 1);
                    const float cc = ctab[s * 32 + pair];
                    const float sn = stab[s * 32 + pair];
                    v = (lm & 1) ? fmaf(vp, sn, v * cc)
                                 : fmaf(-vp, sn, v * cc);
                    ushort_t hh, ll;
                    split2(v, hh, ll);
                    qkh[(size_t)row * 2048 + col] = hh;
                    qkl[(size_t)row * 2048 + col] = ll;
                } else {
                    ushort_t hh, ll;
                    split2(v, hh, ll);
                    const int dg = col - 2 * D_;           // 0..1023
                    const int bh = (row >> 9) * 16 + (dg >> 6);
                    const int d  = dg & 63;
                    const int s  = row & (S_ - 1);
                    vTh[((size_t)bh * 64 + d) * 512 + s] = hh;
                    vTl[((size_t)bh * 64 + d) * 512 + s] = ll;
                }
            }
        }
}

// ---------------------------------------------------------------------------
// Routed fused gate+up MoE GEMM: rows gathered from per-expert token lists.
// Single-buffer 2-barrier staging (proven structure).
// ---------------------------------------------------------------------------
__global__ __launch_bounds__(256) void gateup_idx_kernel(
    const ushort_t* __restrict__ A, const ushort_t* __restrict__ Bgu,
    const int* __restrict__ cnt, const int* __restrict__ tok,
    ushort_t* __restrict__ Hc)
{
    const int e = blockIdx.z;
    const int cntE = cnt[e];
    const int row0 = blockIdx.y * 128;
    if (row0 >= cntE) return;
    const int col0 = blockIdx.x * 128;
    const ushort_t* Bt = Bgu + (size_t)e * GU_ * D_;
    ushort_t* Hp = Hc + (size_t)e * T_ * HID_;

    __shared__ __align__(16) ushort_t As[128 * 32];
    __shared__ __align__(16) ushort_t Bs[128 * 32];
    const int tid = threadIdx.x, w = tid >> 6, lane = tid & 63;
    const int lr = lane >> 2, lc = (lane & 3) * 8;
    const int wm = (w >> 1) * 64, wn = (w & 1) * 64;
    const int lm = lane & 15, lq = lane >> 4;

    floatx4 acc[4][4] = {};

    int r0c = row0 + w * 16 + lr;  if (r0c > cntE - 1) r0c = cntE - 1;
    int r1c = row0 + 64 + w * 16 + lr; if (r1c > cntE - 1) r1c = cntE - 1;
    const ushort_t* Ap0 = A + (size_t)tok[e * T_ + r0c] * D_ + lc;
    const ushort_t* Ap1 = A + (size_t)tok[e * T_ + r1c] * D_ + lc;
    const ushort_t* Bp = Bt + (size_t)(col0 + w * 16 + lr) * D_ + lc;
    ushort_t* lA = As + w * 512;
    ushort_t* lB = Bs + w * 512;

    for (int k0 = 0; k0 < D_; k0 += 32) {
        __syncthreads();
        gl2lds16(Ap0 + k0, lA);
        gl2lds16(Ap1 + k0, lA + 2048);
        gl2lds16(Bp + k0, lB);
        gl2lds16(Bp + k0 + (size_t)64 * D_, lB + 2048);
        __syncthreads();
        bf16x8 a[4], b[4];
#pragma unroll
        for (int i = 0; i < 4; i++)
            a[i] = *(const bf16x8*)(As + (wm + i * 16 + lm) * 32 + lq * 8);
#pragma unroll
        for (int j = 0; j < 4; j++)
            b[j] = *(const bf16x8*)(Bs + (wn + j * 16 + lm) * 32 + lq * 8);
#pragma unroll
        for (int i = 0; i < 4; i++)
#pragma unroll
            for (int j = 0; j < 4; j++)
                acc[i][j] = __builtin_amdgcn_mfma_f32_16x16x32_bf16(a[i], b[j], acc[i][j], 0, 0, 0);
    }

    // epilogue: adjacent lanes hold (gate, up) for the same hidden unit
#pragma unroll
    for (int i = 0; i < 4; i++)
#pragma unroll
        for (int j = 0; j < 4; j++)
#pragma unroll
            for (int r = 0; r < 4; r++) {
                const float v = acc[i][j][r];
                const float vp = __shfl_xor(v, 1);
                const float g = (lm & 1) ? vp : v;
                const float u = (lm & 1) ? v : vp;
                const float h = g / (1.f + __expf(-g)) * u;
                if (!(lm & 1)) {
                    const int row = row0 + wm + i * 16 + lq * 4 + r;
                    const int col = col0 + wn + j * 16 + lm;    // even
                    Hp[(size_t)row * HID_ + (col >> 1)] = f2bf(h);
                }
            }
}

// ---------------------------------------------------------------------------
// Routed MoE down GEMM, split-K: out[tok[r]] += wt[r] * (Hc[e] @ wd[e]^T).
// grid (8, 16, E*2): z -> (expert, k-slice of HID/2). Single-buffer staging.
// ---------------------------------------------------------------------------
__global__ __launch_bounds__(256) void down_idx_kernel(
    const ushort_t* __restrict__ Hc, const ushort_t* __restrict__ Wd,
    const int* __restrict__ cnt, const int* __restrict__ tok,
    const float* __restrict__ wt, float* __restrict__ out)
{
    const int e = blockIdx.z >> 1;
    const int ks = blockIdx.z & 1;
    const int cntE = cnt[e];
    const int row0 = blockIdx.y * 128;
    if (row0 >= cntE) return;
    const int col0 = blockIdx.x * 128;
    const int kBegin = ks * (HID_ / 2);
    const ushort_t* A = Hc + (size_t)e * T_ * HID_;
    const ushort_t* Bt = Wd + (size_t)e * D_ * HID_;

    __shared__ __align__(16) ushort_t As[128 * 32];
    __shared__ __align__(16) ushort_t Bs[128 * 32];
    const int tid = threadIdx.x, w = tid >> 6, lane = tid & 63;
    const int lr = lane >> 2, lc = (lane & 3) * 8;
    const int wm = (w >> 1) * 64, wn = (w & 1) * 64;
    const int lm = lane & 15, lq = lane >> 4;

    floatx4 acc[4][4] = {};

    const ushort_t* Ap = A + (size_t)(row0 + w * 16 + lr) * HID_ + kBegin + lc;
    const ushort_t* Bp = Bt + (size_t)(col0 + w * 16 + lr) * HID_ + kBegin + lc;
    ushort_t* lA = As + w * 512;
    ushort_t* lB = Bs + w * 512;

    for (int k0 = 0; k0 < HID_ / 2; k0 += 32) {
        __syncthreads();
        gl2lds16(Ap + k0, lA);
        gl2lds16(Ap + k0 + (size_t)64 * HID_, lA + 2048);
        gl2lds16(Bp + k0, lB);
        gl2lds16(Bp + k0 + (size_t)64 * HID_, lB + 2048);
        __syncthreads();
        bf16x8 a[4], b[4];
#pragma unroll
        for (int i = 0; i < 4; i++)
            a[i] = *(const bf16x8*)(As + (wm + i * 16 + lm) * 32 + lq * 8);
#pragma unroll
        for (int j = 0; j < 4; j++)
            b[j] = *(const bf16x8*)(Bs + (wn + j * 16 + lm) * 32 + lq * 8);
#pragma unroll
        for (int i = 0; i < 4; i++)
#pragma unroll
            for (int j = 0; j < 4; j++)
                acc[i][j] = __builtin_amdgcn_mfma_f32_16x16x32_bf16(a[i], b[j], acc[i][j], 0, 0, 0);
    }

#pragma unroll
    for (int i = 0; i < 4; i++)
#pragma unroll
        for (int r = 0; r < 4; r++) {
            const int row = row0 + wm + i * 16 + lq * 4 + r;
            if (row < cntE) {
                const int t = tok[e * T_ + row];
                const float scale = wt[e * T_ + row];
#pragma unroll
                for (int j = 0; j < 4; j++) {
                    const int col = col0 + wn + j * 16 + lm;
                    atomicAdd(&out[(size_t)t * D_ + col], scale * acc[i][j][r]);
                }
            }
        }
}

// ---------------------------------------------------------------------------
// RoPE cos/sin tables (np f32 semantics via f64 pow/cos/sin)
// ---------------------------------------------------------------------------
__global__ __launch_bounds__(256) void rope_table_kernel(
    float* __restrict__ ctab, float* __restrict__ stab)
{
    const int i = blockIdx.x * 256 + threadIdx.x;   // S_*32
    if (i >= S_ * 32) return;
    const int s = i >> 5, p = i & 31;
    const double e = (double)(2 * p) / 64.0;
    const float pf = (float)pow(10000.0, e);
    const float invf = 1.0f / pf;
    const float fr = (float)s * invf;
    ctab[i] = (float)cos((double)fr);
    stab[i] = (float)sin((double)fr);
}

// ---------------------------------------------------------------------------
// Fused flash attention — two-word bf16 MFMA, online softmax, single pass.
// Inputs are PRE-SPLIT hi/lo bf16 planes (qk: [T][2048] rotated q|k;
// vT: [bh][64][512]) so the loop does pure 16B vector staging.
// Grid (bh=64, qt=16), 256 thr = 4 waves; wave w owns kv/d chunk w*16..+15.
// ---------------------------------------------------------------------------
__global__ __launch_bounds__(256, 4) void attn_fused_kernel(
    const ushort_t* __restrict__ qkh, const ushort_t* __restrict__ qkl,
    const ushort_t* __restrict__ vTh, const ushort_t* __restrict__ vTl,
    ushort_t* __restrict__ aoh, ushort_t* __restrict__ aol)
{
    const int bh = blockIdx.x;                 // b*16+h
    const int qt = blockIdx.y;
    const int b = bh >> 4, h = bh & 15;
    const int q0 = qt * 32;
    const int nchunk = (qt >> 1) + 1;

    // bf16 hi/lo tiles, row stride 72 (pad 8) keeps b128 reads 16B-aligned
    __shared__ __align__(16) ushort_t qsh[32 * 72], qsl[32 * 72];  // Q rows (q, d)
    __shared__ __align__(16) ushort_t kvh[64 * 72], kvl[64 * 72];  // K rows, then V^T rows
    __shared__ __align__(16) ushort_t psh[32 * 72], psl[32 * 72];  // P rows (q, kv)
    __shared__ __align__(16) float redm[32][4];      // per-wave row max
    __shared__ __align__(16) float redl[32][4];      // per-wave row sum

    const int tid = threadIdx.x, w = tid >> 6, lane = tid & 63;
    const int lm = lane & 15, lq = lane >> 4;
    const size_t vbase = (size_t)bh * (HD_ * S_);

    // ---- stage Q once: pure 16B copies from planes
    {
        const int row = tid >> 3, g = tid & 7;
        const size_t src = (size_t)(b * S_ + q0 + row) * 2048 + h * HD_ + g * 8;
        *(uint4*)(qsh + row * 72 + g * 8) = *(const uint4*)(qkh + src);
        *(uint4*)(qsl + row * 72 + g * 8) = *(const uint4*)(qkl + src);
    }

    // running state: rows q = i*16 + lq*4 + r, col d = w*16 + lm
    float mrun[2][4], lrun[2][4];
    floatx4 oacc[2] = {};
#pragma unroll
    for (int i = 0; i < 2; i++)
#pragma unroll
        for (int r = 0; r < 4; r++) { mrun[i][r] = -INFINITY; lrun[i][r] = 0.f; }

    for (int c = 0; c < nchunk; c++) {
        const int c0 = c * 64;

        // ---- stage K chunk: 16B copies from planes into shared K/V buffer
#pragma unroll
        for (int it = 0; it < 2; it++) {
            const int i = tid + it * 256;
            const int row = i >> 3, g = i & 7;
            const size_t src = (size_t)(b * S_ + c0 + row) * 2048 + 1024 + h * HD_ + g * 8;
            *(uint4*)(kvh + row * 72 + g * 8) = *(const uint4*)(qkh + src);
            *(uint4*)(kvl + row * 72 + g * 8) = *(const uint4*)(qkl + src);
        }
        // ---- prefetch V^T rows into registers; latency hides under QK
        uint4 vrh[2], vrl[2];
#pragma unroll
        for (int it = 0; it < 2; it++) {
            const int i = tid + it * 256;
            const int row = i >> 3, g = i & 7;     // row = d (0..63)
            const size_t src = vbase + (size_t)row * S_ + c0 + g * 8;
            vrh[it] = *(const uint4*)(vTh + src);
            vrl[it] = *(const uint4*)(vTl + src);
        }
        __syncthreads();   // K (and Q on first iter) visible

        // ---- scores: wave w -> S[32 q][16 kv] chunk; 3 MFMAs per product
        floatx4 acc[2] = {};
#pragma unroll
        for (int k0 = 0; k0 < 64; k0 += 32) {
            const bf16x8 bh16 = *(const bf16x8*)(kvh + (w * 16 + lm) * 72 + k0 + lq * 8);
            const bf16x8 bl16 = *(const bf16x8*)(kvl + (w * 16 + lm) * 72 + k0 + lq * 8);
#pragma unroll
            for (int i = 0; i < 2; i++) {
                const bf16x8 ah = *(const bf16x8*)(qsh + (i * 16 + lm) * 72 + k0 + lq * 8);
                const bf16x8 al = *(const bf16x8*)(qsl + (i * 16 + lm) * 72 + k0 + lq * 8);
                acc[i] = __builtin_amdgcn_mfma_f32_16x16x32_bf16(ah, bh16, acc[i], 0, 0, 0);
                acc[i] = __builtin_amdgcn_mfma_f32_16x16x32_bf16(al, bh16, acc[i], 0, 0, 0);
                acc[i] = __builtin_amdgcn_mfma_f32_16x16x32_bf16(ah, bl16, acc[i], 0, 0, 0);
            }
        }

        // ---- mask + scale, per-row max over this wave's 16 kv
        float sv[2][4];
        const int kvg = c0 + w * 16 + lm;
#pragma unroll
        for (int i = 0; i < 2; i++)
#pragma unroll
            for (int r = 0; r < 4; r++) {
                const int qg = q0 + i * 16 + lq * 4 + r;
                float v = (kvg <= qg) ? acc[i][r] * 0.125f : -INFINITY;
                sv[i][r] = v;
#pragma unroll
                for (int off = 1; off < 16; off <<= 1) v = fmaxf(v, __shfl_xor(v, off));
                if (lm == 0) redm[i * 16 + lq * 4 + r][w] = v;
            }
        __syncthreads();   // redm complete; all K reads done

        // ---- stage V^T from registers (overwrites K) — vector stores
#pragma unroll
        for (int it = 0; it < 2; it++) {
            const int i = tid + it * 256;
            const int row = i >> 3, g = i & 7;
            *(uint4*)(kvh + row * 72 + g * 8) = vrh[it];
            *(uint4*)(kvl + row * 72 + g * 8) = vrl[it];
        }

        // ---- online softmax: new row max, p = exp(s - m'), rescale factor
        float sclr[2][4];
#pragma unroll
        for (int i = 0; i < 2; i++)
#pragma unroll
            for (int r = 0; r < 4; r++) {
                const int q = i * 16 + lq * 4 + r;
                const float4 m4 = *(const float4*)&redm[q][0];
                const float Mc = fmaxf(fmaxf(m4.x, m4.y), fmaxf(m4.z, m4.w));
                const float Mn = fmaxf(mrun[i][r], Mc);
                const float p = expf(sv[i][r] - Mn);
                ushort_t ph, pl;
                split2(p, ph, pl);
                psh[q * 72 + w * 16 + lm] = ph;
                psl[q * 72 + w * 16 + lm] = pl;
                float sum = p;
#pragma unroll
                for (int off = 1; off < 16; off <<= 1) sum += __shfl_xor(sum, off);
                if (lm == 0) redl[q][w] = sum;
                sclr[i][r] = expf(mrun[i][r] - Mn);   // 0 on first chunk
                mrun[i][r] = Mn;
            }
        __syncthreads();   // ps, V^T, redl ready

        // ---- update l, rescale O
#pragma unroll
        for (int i = 0; i < 2; i++)
#pragma unroll
            for (int r = 0; r < 4; r++) {
                const int q = i * 16 + lq * 4 + r;
                const float4 l4 = *(const float4*)&redl[q][0];
                const float lc = l4.x + l4.y + l4.z + l4.w;
                lrun[i][r] = lrun[i][r] * sclr[i][r] + lc;
                oacc[i][r] *= sclr[i][r];
            }

        // ---- PV: O[32 q][16 d chunk w] += (Ph+Pl) · (Vh+Vl)^T
#pragma unroll
        for (int k0 = 0; k0 < 64; k0 += 32) {
            const bf16x8 bh16 = *(const bf16x8*)(kvh + (w * 16 + lm) * 72 + k0 + lq * 8);
            const bf16x8 bl16 = *(const bf16x8*)(kvl + (w * 16 + lm) * 72 + k0 + lq * 8);
#pragma unroll
            for (int i = 0; i < 2; i++) {
                const bf16x8 ah = *(const bf16x8*)(psh + (i * 16 + lm) * 72 + k0 + lq * 8);
                const bf16x8 al = *(const bf16x8*)(psl + (i * 16 + lm) * 72 + k0 + lq * 8);
                oacc[i] = __builtin_amdgcn_mfma_f32_16x16x32_bf16(ah, bh16, oacc[i], 0, 0, 0);
                oacc[i] = __builtin_amdgcn_mfma_f32_16x16x32_bf16(al, bh16, oacc[i], 0, 0, 0);
                oacc[i] = __builtin_amdgcn_mfma_f32_16x16x32_bf16(ah, bl16, oacc[i], 0, 0, 0);
            }
        }
        __syncthreads();   // PV reads done before next chunk overwrites kv/ps
    }

    // ---- epilogue: normalize and emit hi/lo bf16 planes
    const int col = h * HD_ + w * 16 + lm;
#pragma unroll
    for (int i = 0; i < 2; i++)
#pragma unroll
        for (int r = 0; r < 4; r++) {
            const int q = i * 16 + lq * 4 + r;
            const int t = b * S_ + q0 + q;
            const float v = oacc[i][r] / lrun[i][r];
            ushort_t hh, ll;
            split2(v, hh, ll);
            aoh[(size_t)t * D_ + col] = hh;
            aol[(size_t)t * D_ + col] = ll;
        }
}

__global__ void zero_route_kernel(int* __restrict__ cnt)
{
    if (threadIdx.x < 8) cnt[threadIdx.x] = 0;
}

// ---------------------------------------------------------------------------
// dist = probs.mean(0); lb = E * sum(dist^2); writes out tail.
// ---------------------------------------------------------------------------
__global__ __launch_bounds__(256) void reduce_dist_kernel(
    const float* __restrict__ probs, float* __restrict__ out)
{
    __shared__ float part[256];
    __shared__ float dist8[8];
    const int tid = threadIdx.x;
    const int e = tid & 7, chunk = tid >> 3;   // 32 chunks
    float s = 0.f;
    for (int t = chunk; t < T_; t += 32) s += probs[t * 8 + e];
    part[tid] = s;
    __syncthreads();
    if (tid < 8) {
        float tot = 0.f;
        for (int c = 0; c < 32; c++) tot += part[c * 8 + tid];
        const float dv = tot * (1.0f / T_);
        dist8[tid] = dv;
        out[(size_t)T_ * D_ + 1 + tid] = dv;
    }
    __syncthreads();
    if (tid == 0) {
        float s2 = 0.f;
        for (int k = 0; k < 8; k++) s2 += dist8[k] * dist8[k];
        out[(size_t)T_ * D_] = (float)E_ * s2;
    }
}

// ---------------------------------------------------------------------------
// Launch
// ---------------------------------------------------------------------------
extern "C" void kernel_launch(void* const* d_in, const int* in_sizes, int n_in,
                              void* d_out, int out_size, void* d_ws, size_t ws_size,
                              hipStream_t stream)
{
    const float* x      = (const float*)d_in[0];
    const float* ln1_g  = (const float*)d_in[1];
    const float* ln1_b  = (const float*)d_in[2];
    const float* ln2_g  = (const float*)d_in[3];
    const float* ln2_b  = (const float*)d_in[4];
    const float* w_qkv  = (const float*)d_in[5];
    const float* w_o    = (const float*)d_in[6];
    const float* gate_w = (const float*)d_in[7];
    const float* w_gate = (const float*)d_in[8];
    const float* w_up   = (const float*)d_in[9];
    const float* w_down = (const float*)d_in[10];
    float* out = (float*)d_out;

    char* ws = (char*)d_ws;
    size_t off = 0;
    auto alloc = [&](size_t bytes) { size_t o = off; off += (bytes + 255) & ~(size_t)255; return o; };
    // persistent-through-MoE region
    ushort_t* wguT  = (ushort_t*)(ws + alloc((size_t)E_ * GU_ * D_ * 2));   // 58.7 MB
    ushort_t* wdT   = (ushort_t*)(ws + alloc((size_t)E_ * D_ * HID_ * 2));  // 29.4 MB
    ushort_t* xnh   = (ushort_t*)(ws + alloc((size_t)T_ * D_ * 4));         // hi+lo planes
    ushort_t* xnl   = xnh + (size_t)T_ * D_;
    ushort_t* xn2   = (ushort_t*)(ws + alloc((size_t)T_ * D_ * 2));
    int*      cnt   = (int*)     (ws + alloc(64));
    int*      tok   = (int*)     (ws + alloc((size_t)E_ * T_ * 4));
    float*    wt    = (float*)   (ws + alloc((size_t)E_ * T_ * 4));
    float*    probs = (float*)   (ws + alloc((size_t)T_ * E_ * 4));
    float*    ctab  = (float*)   (ws + alloc((size_t)S_ * 32 * 4));
    float*    stab  = (float*)   (ws + alloc((size_t)S_ * 32 * 4));
    // scratch union (59 MB, aliased by lifetime):
    //   A (QKV GEMM):  wqkvT hi/lo [0,12.58M) read; qkh/qkl [12.58M,29.36M)
    //                  + vT hi/lo [29.36M,37.75M) written by fused epilogue
    //   B (attn):      qkh/qkl/vT read; aoh/aol [37.75M,46.14M) written
    //   C (W_O):       x1 [0,8.39M) + woT [8.39M,12.58M) (wqkvT dead);
    //                  aoh/aol read
    //   D (MoE):       Hc [0,58.7M) (everything else dead)
    const size_t scratch0 = alloc((size_t)59 << 20);
    char* sc = ws + scratch0;
    ushort_t* wqkvTh= (ushort_t*)(sc);
    ushort_t* wqkvTl= wqkvTh + (size_t)D3_ * D_;                  // ends 12,582,912
    ushort_t* qkh   = (ushort_t*)(sc + 12582912);
    ushort_t* qkl   = qkh + (size_t)T_ * 2048;                    // ends 29,360,128
    ushort_t* vTh   = (ushort_t*)(sc + 29360128);
    ushort_t* vTl   = vTh + (size_t)64 * HD_ * S_;                // ends 37,748,736
    ushort_t* aoh   = (ushort_t*)(sc + 37748736);
    ushort_t* aol   = aoh + (size_t)T_ * D_;                      // ends 46,137,344
    float*    x1    = (float*)   (sc);                            // W_O phase
    ushort_t* woTh  = (ushort_t*)(sc + 8388608);
    ushort_t* woTl  = woTh + (size_t)D_ * D_;
    ushort_t* Hc    = (ushort_t*)(sc);                            // MoE phase
    (void)ws_size; (void)in_sizes; (void)n_in; (void)out_size;

    // weight transposes -> bf16 (N x K); gate/up interleaved into wguT
    hipLaunchKernelGGL(transpose_bf16_kernel, dim3(HID_ / 64, D_ / 64, E_), dim3(256), 0, stream,
                       w_gate, wguT, D_, HID_, 2, 0, (long)GU_ * D_);
    hipLaunchKernelGGL(transpose_bf16_kernel, dim3(HID_ / 64, D_ / 64, E_), dim3(256), 0, stream,
                       w_up, wguT, D_, HID_, 2, 1, (long)GU_ * D_);
    hipLaunchKernelGGL(transpose_bf16_kernel, dim3(D_ / 64, HID_ / 64, E_), dim3(256), 0, stream,
                       w_down, wdT, HID_, D_, 1, 0, (long)D_ * HID_);

    // w_qkv (D x 3D) -> hi/lo bf16 planes (3D x D)
    hipLaunchKernelGGL(transpose_split_kernel, dim3(D3_ / 64, D_ / 64), dim3(256), 0, stream,
                       w_qkv, wqkvTh, wqkvTl, D_, D3_);

    // RoPE tables
    hipLaunchKernelGGL(rope_table_kernel, dim3((S_ * 32 + 255) / 256), dim3(256), 0, stream,
                       ctab, stab);

    // LN1 -> hi/lo bf16 planes (no gating)
    hipLaunchKernelGGL(ln_kernel, dim3(T_), dim3(256), 0, stream,
                       x, ln1_g, ln1_b, (ushort_t*)nullptr, xnh, xnl,
                       (const float*)nullptr, (int*)nullptr, (int*)nullptr,
                       (float*)nullptr, (float*)nullptr);

    // QKV GEMM (128x64 tiles, 768 blocks = 3/CU) with fused RoPE epilogue
    hipLaunchKernelGGL(qkv_rope_gemm_kernel, dim3(D3_ / 64, T_ / 128), dim3(256), 0, stream,
                       xnh, xnl, wqkvTh, wqkvTl, ctab, stab, qkh, qkl, vTh, vTl);

    // fused flash attention -> attn output hi/lo planes
    hipLaunchKernelGGL(attn_fused_kernel, dim3(64, 16), dim3(256), 0, stream,
                       qkh, qkl, vTh, vTl, aoh, aol);

    // w_o (D x D) -> hi/lo bf16 planes (wqkvT dead now)
    hipLaunchKernelGGL(transpose_split_kernel, dim3(D_ / 64, D_ / 64), dim3(256), 0, stream,
                       w_o, woTh, woTl, D_, D_);

    // W_O two-word bf16 MFMA GEMM (128x64 tiles, 256 blocks = 1/CU)
    hipLaunchKernelGGL(gemm2w_n64_kernel, dim3(D_ / 64, T_ / 128), dim3(256), 0, stream,
                       aoh, aol, woTh, woTl, x, x1, out, D_);

    // routing counters must be zero before LN2's fused gating
    hipLaunchKernelGGL(zero_route_kernel, dim3(1), dim3(64), 0, stream, cnt);

    // LN2 (bf16) with FUSED gating + routing (bitwise-identical gate loop)
    hipLaunchKernelGGL(ln_kernel, dim3(T_), dim3(256), 0, stream,
                       x1, ln2_g, ln2_b, xn2, (ushort_t*)nullptr, (ushort_t*)nullptr,
                       gate_w, cnt, tok, wt, probs);

    // aux outputs
    hipLaunchKernelGGL(reduce_dist_kernel, dim3(1), dim3(256), 0, stream, probs, out);

    // MoE routed: fused gate+up (+silu), then weighted down (split-K=2)
    hipLaunchKernelGGL(gateup_idx_kernel, dim3(GU_ / 128, T_ / 128, E_), dim3(256), 0, stream,
                       xn2, wguT, cnt, tok, Hc);
    hipLaunchKernelGGL(down_idx_kernel, dim3(D_ / 128, T_ / 128, E_ * 2), dim3(256), 0, stream,
                       Hc, wdT, cnt, tok, wt, out);
}